// Round 9
// baseline (447.039 us; speedup 1.0000x reference)
//
#include <hip/hip_runtime.h>
#include <cmath>

#define CC 64
#define HH 512
#define WWID 512
#define HWSZ (HH*WWID)
#define DEPTH 4

typedef __attribute__((ext_vector_type(8))) short short8;
typedef __attribute__((ext_vector_type(4))) float floatx4;

__device__ inline unsigned short f2bf(float f){
  unsigned int u = __float_as_uint(f);
  u += 0x7FFF + ((u >> 16) & 1);          // round-to-nearest-even
  return (unsigned short)(u >> 16);
}
__device__ inline float bf2f(unsigned short h){
  return __uint_as_float(((unsigned int)h) << 16);
}
// unpack a uint holding 2 bf16 (elem0 = low half, elem1 = high half)
__device__ inline float bfu_lo(unsigned int u){ return __uint_as_float(u << 16); }
__device__ inline float bfu_hi(unsigned int u){ return __uint_as_float(u & 0xFFFF0000u); }

// ---------------- init ----------------
__global__ void k_init(const float* __restrict__ ww,
                       float* __restrict__ ctab, float* __restrict__ stab,
                       unsigned short* __restrict__ trigBh, unsigned short* __restrict__ trigBl,
                       unsigned short* __restrict__ trigTh, unsigned short* __restrict__ trigTl,
                       unsigned short* __restrict__ Whi, unsigned short* __restrict__ Wlo){
  int idx = blockIdx.x*256 + threadIdx.x;
  if (idx < 8192){
    int pos = idx >> 4, k = idx & 15;
    int r = (pos * k) & 511;
    double ang = (2.0 * 3.14159265358979323846 / 512.0) * (double)r;
    float c = (float)cos(ang), s = (float)sin(ang);
    ctab[idx] = c;  stab[idx] = s;
    unsigned short ch = f2bf(c), sh = f2bf(s);
    unsigned short cl = f2bf(c - bf2f(ch)), sl = f2bf(s - bf2f(sh));
    trigBh[pos*32 + 2*k]     = ch;  trigBl[pos*32 + 2*k]     = cl;
    trigBh[pos*32 + 2*k + 1] = sh;  trigBl[pos*32 + 2*k + 1] = sl;
    trigTh[(2*k)*512 + pos]   = ch;  trigTl[(2*k)*512 + pos]   = cl;
    trigTh[(2*k+1)*512 + pos] = sh;  trigTl[(2*k+1)*512 + pos] = sl;
  } else {
    int t = idx - 8192;                   // < 4*64*64, flat [d][o][i]
    float v = ww[t];
    unsigned short h = f2bf(v);
    Whi[t] = h;  Wlo[t] = f2bf(v - bf2f(h));
  }
}

// ---------------- lift: x[c,h,w] = proj_w[c]*q[h,w] + proj_b[c], stored split-bf16 ----------------
__global__ void k_lift(const float4* __restrict__ q, const float* __restrict__ pw,
                       const float* __restrict__ pb,
                       unsigned int* __restrict__ xh, unsigned int* __restrict__ xl){
  int idx = blockIdx.x*256 + threadIdx.x;     // < 64*HW/4
  int c = idx >> 16, p = idx & (HWSZ/4 - 1);
  float4 v = q[p];
  float a = pw[c], b = pb[c];
  v.x = fmaf(a, v.x, b); v.y = fmaf(a, v.y, b);
  v.z = fmaf(a, v.z, b); v.w = fmaf(a, v.w, b);
  unsigned short h0 = f2bf(v.x), h1 = f2bf(v.y), h2 = f2bf(v.z), h3 = f2bf(v.w);
  unsigned short l0 = f2bf(v.x - bf2f(h0)), l1 = f2bf(v.y - bf2f(h1));
  unsigned short l2 = f2bf(v.z - bf2f(h2)), l3 = f2bf(v.w - bf2f(h3));
  uint2 H = make_uint2((unsigned)h0 | ((unsigned)h1<<16), (unsigned)h2 | ((unsigned)h3<<16));
  uint2 L = make_uint2((unsigned)l0 | ((unsigned)l1<<16), (unsigned)l2 | ((unsigned)l3<<16));
  ((uint2*)xh)[c*65536 + p] = H;
  ((uint2*)xl)[c*65536 + p] = L;
}

// ---------------- A: DFT along w as split-bf16 MFMA GEMM (x already split: pure copy staging) ----------------
#define APITCH 136   // shorts/row: 272 B rows, 16B-aligned; 68-dword stride -> 2-way bank alias (free)
__global__ __launch_bounds__(256) void k_dftw(
    const unsigned int* __restrict__ xh, const unsigned int* __restrict__ xl,
    const unsigned short* __restrict__ trigTh, const unsigned short* __restrict__ trigTl,
    float* __restrict__ X1f){
  __shared__ unsigned short Ahs[64*APITCH], Als[64*APITCH];
  __shared__ unsigned short Bhs[32*APITCH], Bls[32*APITCH];
  int row0 = blockIdx.x * 64;                 // 64 (c,h) rows per block
  int t = threadIdx.x;
  int g = t >> 6, lm = t & 15, lq = (t >> 4) & 3;

  floatx4 acc[2] = {{0.f,0.f,0.f,0.f},{0.f,0.f,0.f,0.f}};

  for (int kc = 0; kc < 4; ++kc){             // K chunks of 128
    {                                         // stage A: raw uint4 copies (no conversion)
      int r = t >> 2, q = t & 3;
      size_t s4 = (size_t)(row0 + r)*64 + kc*16 + q*4;   // uint4 index (8 bf16 each)
      const uint4* sh4 = (const uint4*)xh + s4;
      const uint4* sl4 = (const uint4*)xl + s4;
      uint4* dh = (uint4*)&Ahs[r*APITCH + q*32];
      uint4* dl = (uint4*)&Als[r*APITCH + q*32];
      #pragma unroll
      for (int u = 0; u < 4; ++u){ dh[u] = sh4[u]; dl[u] = sl4[u]; }
    }
    {                                         // stage B: trig rows copy
      int j = t >> 3, q = t & 7;
      const unsigned int* sh = (const unsigned int*)trigTh + j*256 + kc*64 + q*8;
      const unsigned int* sl = (const unsigned int*)trigTl + j*256 + kc*64 + q*8;
      unsigned int* dh = (unsigned int*)&Bhs[j*APITCH + q*16];
      unsigned int* dl = (unsigned int*)&Bls[j*APITCH + q*16];
      #pragma unroll
      for (int u = 0; u < 8; ++u){ dh[u] = sh[u]; dl[u] = sl[u]; }
    }
    __syncthreads();
    #pragma unroll
    for (int ks = 0; ks < 4; ++ks){
      short8 ah = *(const short8*)&Ahs[(g*16 + lm)*APITCH + ks*32 + lq*8];
      short8 al = *(const short8*)&Als[(g*16 + lm)*APITCH + ks*32 + lq*8];
      #pragma unroll
      for (int nt = 0; nt < 2; ++nt){
        short8 bh = *(const short8*)&Bhs[(nt*16 + lm)*APITCH + ks*32 + lq*8];
        short8 bl = *(const short8*)&Bls[(nt*16 + lm)*APITCH + ks*32 + lq*8];
        acc[nt] = __builtin_amdgcn_mfma_f32_16x16x32_bf16(ah, bh, acc[nt], 0, 0, 0);
        acc[nt] = __builtin_amdgcn_mfma_f32_16x16x32_bf16(ah, bl, acc[nt], 0, 0, 0);
        acc[nt] = __builtin_amdgcn_mfma_f32_16x16x32_bf16(al, bh, acc[nt], 0, 0, 0);
      }
    }
    __syncthreads();
  }
  #pragma unroll
  for (int nt = 0; nt < 2; ++nt){
    int j = nt*16 + lm;
    float sgn = (j & 1) ? -1.f : 1.f;
    #pragma unroll
    for (int rg = 0; rg < 4; ++rg){
      int m = g*16 + lq*4 + rg;
      X1f[(size_t)(row0 + m)*32 + j] = sgn * acc[nt][rg];
    }
  }
}

// ---------------- B1: DFT along h, fused reduce (2 h-chunks, 2-way ILP) ----------------
__global__ void k_dfth(const float2* __restrict__ X1, const float* __restrict__ ct,
                       const float* __restrict__ st, float2* __restrict__ Xfp){
  int i = blockIdx.x, ch = blockIdx.y;        // 64 x 2
  int m = threadIdx.x >> 4, n = threadIdx.x & 15;
  float ar0=0.f, ai0=0.f, ar1=0.f, ai1=0.f;
  int h0 = ch * 256;
  #pragma unroll 4
  for (int hh = 0; hh < 256; hh += 2){
    int h = h0 + hh;
    float2 v0 = X1[(i*512 + h)*16 + n];
    float c0 = ct[h*16 + m], s0 = st[h*16 + m];
    ar0 += v0.x*c0 + v0.y*s0;  ai0 += v0.y*c0 - v0.x*s0;
    float2 v1 = X1[(i*512 + h + 1)*16 + n];
    float c1 = ct[(h+1)*16 + m], s1 = st[(h+1)*16 + m];
    ar1 += v1.x*c1 + v1.y*s1;  ai1 += v1.y*c1 - v1.x*s1;
  }
  Xfp[(ch*64 + i)*256 + threadIdx.x] = make_float2(ar0+ar1, ai0+ai1);
}

// ---------------- B2: mode contraction, single-shot (weights read once, no partials) ----------------
__global__ void k_contract(const float2* __restrict__ Xfp,
                           const float* __restrict__ wr, const float* __restrict__ wi,
                           float2* __restrict__ Y){
  int o = blockIdx.x;
  int mn = blockIdx.y*64 + threadIdx.x;
  float ar0=0.f, ai0=0.f, ar1=0.f, ai1=0.f;
  #pragma unroll 4
  for (int i = 0; i < 64; i += 2){
    float2 xa = Xfp[i*256 + mn],       xb = Xfp[(64 + i)*256 + mn];
    float xr = xa.x + xb.x, xi = xa.y + xb.y;
    float w0r = wr[(i*64 + o)*256 + mn], w0i = wi[(i*64 + o)*256 + mn];
    ar0 += xr*w0r - xi*w0i;  ai0 += xr*w0i + xi*w0r;
    float2 xc = Xfp[(i+1)*256 + mn],   xd = Xfp[(65 + i)*256 + mn];
    float xr1 = xc.x + xd.x, xi1 = xc.y + xd.y;
    float w1r = wr[((i+1)*64 + o)*256 + mn], w1i = wi[((i+1)*64 + o)*256 + mn];
    ar1 += xr1*w1r - xi1*w1i;  ai1 += xr1*w1i + xi1*w1r;
  }
  const float sc = 1.f/262144.f;
  Y[o*256 + mn] = make_float2((ar0+ar1)*sc, (ai0+ai1)*sc);
}

// ---------------- B3: inverse DFT along h -> T, split bf16 hi/lo, sign-folded ----------------
__global__ void k_idfth(const float2* __restrict__ Y, const float* __restrict__ ct,
                        const float* __restrict__ st,
                        unsigned short* __restrict__ Thi, unsigned short* __restrict__ Tlo){
  int idx = blockIdx.x*256 + threadIdx.x;     // (h*64+o)*16+n
  int n = idx & 15, o = (idx >> 4) & 63, h = idx >> 10;
  float ar = 0.f, ai = 0.f;
  #pragma unroll
  for (int m = 0; m < 16; ++m){
    float2 y = Y[(o<<8) + (m<<4) + n];
    float c = ct[h*16 + m], s = st[h*16 + m];
    ar += y.x*c - y.y*s;
    ai += y.x*s + y.y*c;
  }
  float tr = ar, ts = -ai;
  unsigned short rh = f2bf(tr), sh = f2bf(ts);
  size_t base = ((size_t)(h*64 + o))*32 + 2*n;
  Thi[base] = rh;  Thi[base+1] = sh;
  Tlo[base] = f2bf(tr - bf2f(rh));  Tlo[base+1] = f2bf(ts - bf2f(sh));
}

// ---------------- C: combine GEMM (K=96), split-bf16 3-pass, x stored pre-split ----------------
#define PITCH 104   // 208 B rows: 16B-aligned, 2-way bank alias (free)
__global__ __launch_bounds__(256) void k_combine(
    unsigned short* __restrict__ xh, unsigned short* __restrict__ xl,
    const unsigned short* __restrict__ Whid, const unsigned short* __restrict__ Wlod,
    const unsigned short* __restrict__ Thi,  const unsigned short* __restrict__ Tlo,
    const unsigned short* __restrict__ trigBh, const unsigned short* __restrict__ trigBl,
    const float* __restrict__ wb)
{
  __shared__ unsigned short Ah[64*PITCH], Al[64*PITCH];   // rows o, k 0..95
  __shared__ unsigned short Bh[64*PITCH], Bl[64*PITCH];   // rows w(pixel), k 0..95
  int h  = blockIdx.y;
  int w0 = blockIdx.x * 64;
  int t  = threadIdx.x;

  {   // B x-part: ushort loads (coalesced along w), pure pack (no conversion)
    int wl = t & 63, ig = t >> 6;
    const unsigned short* bh = xh + (size_t)h*512 + w0 + wl;
    const unsigned short* bl = xl + (size_t)h*512 + w0 + wl;
    #pragma unroll
    for (int ii = 0; ii < 16; ii += 2){
      int i0 = ig*16 + ii;
      unsigned int a0 = bh[(size_t)i0*HWSZ], a1 = bh[(size_t)(i0+1)*HWSZ];
      unsigned int c0 = bl[(size_t)i0*HWSZ], c1 = bl[(size_t)(i0+1)*HWSZ];
      *(unsigned int*)&Bh[wl*PITCH + i0] = a0 | (a1 << 16);
      *(unsigned int*)&Bl[wl*PITCH + i0] = c0 | (c1 << 16);
    }
  }
  {   // B trig-part: rows w, k=64..95
    int row = t >> 2, qq = t & 3;
    const unsigned int* sh = (const unsigned int*)trigBh + (size_t)(w0+row)*16 + qq*4;
    const unsigned int* sl = (const unsigned int*)trigBl + (size_t)(w0+row)*16 + qq*4;
    unsigned int* dh = (unsigned int*)&Bh[row*PITCH + 64] + qq*4;
    unsigned int* dl = (unsigned int*)&Bl[row*PITCH + 64] + qq*4;
    #pragma unroll
    for (int u = 0; u < 4; ++u){ dh[u] = sh[u]; dl[u] = sl[u]; }
  }
  {   // A W-part: rows o, k=0..63
    int o = t >> 2, q8 = t & 3;
    const unsigned int* sh = (const unsigned int*)Whid + o*32 + q8*8;
    const unsigned int* sl = (const unsigned int*)Wlod + o*32 + q8*8;
    unsigned int* dh = (unsigned int*)&Ah[o*PITCH] + q8*8;
    unsigned int* dl = (unsigned int*)&Al[o*PITCH] + q8*8;
    #pragma unroll
    for (int u = 0; u < 8; ++u){ dh[u] = sh[u]; dl[u] = sl[u]; }
  }
  {   // A T-part: rows o, k=64..95
    int o = t >> 2, q4 = t & 3;
    const unsigned int* sh = (const unsigned int*)Thi + (size_t)h*1024 + o*16 + q4*4;
    const unsigned int* sl = (const unsigned int*)Tlo + (size_t)h*1024 + o*16 + q4*4;
    unsigned int* dh = (unsigned int*)&Ah[o*PITCH + 64] + q4*4;
    unsigned int* dl = (unsigned int*)&Al[o*PITCH + 64] + q4*4;
    #pragma unroll
    for (int u = 0; u < 4; ++u){ dh[u] = sh[u]; dl[u] = sl[u]; }
  }
  __syncthreads();

  int g  = t >> 6;          // wave -> m-tile (o-rows g*16..+15)
  int lm = t & 15;
  int lq = (t >> 4) & 3;

  floatx4 acc[4] = {{0.f,0.f,0.f,0.f},{0.f,0.f,0.f,0.f},{0.f,0.f,0.f,0.f},{0.f,0.f,0.f,0.f}};

  #pragma unroll
  for (int ks = 0; ks < 3; ++ks){
    short8 af = *(const short8*)&Ah[(g*16 + lm)*PITCH + ks*32 + lq*8];
    short8 al = *(const short8*)&Al[(g*16 + lm)*PITCH + ks*32 + lq*8];
    #pragma unroll
    for (int nt = 0; nt < 4; ++nt){
      short8 bf = *(const short8*)&Bh[(nt*16 + lm)*PITCH + ks*32 + lq*8];
      short8 bl = *(const short8*)&Bl[(nt*16 + lm)*PITCH + ks*32 + lq*8];
      acc[nt] = __builtin_amdgcn_mfma_f32_16x16x32_bf16(af, bf, acc[nt], 0, 0, 0);
      acc[nt] = __builtin_amdgcn_mfma_f32_16x16x32_bf16(af, bl, acc[nt], 0, 0, 0);
      acc[nt] = __builtin_amdgcn_mfma_f32_16x16x32_bf16(al, bf, acc[nt], 0, 0, 0);
    }
  }

  // epilogue: bias + tanh-gelu + split-bf16 in-place store
  #pragma unroll
  for (int nt = 0; nt < 4; ++nt){
    int w = w0 + nt*16 + lm;
    #pragma unroll
    for (int rg = 0; rg < 4; ++rg){
      int o = g*16 + lq*4 + rg;
      float u = acc[nt][rg] + wb[o];
      float z = 0.7978845608028654f * fmaf(0.044715f, u*u*u, u);
      float e = __expf(2.f*z);
      float gl = u - __fdividef(u, e + 1.f);
      size_t base = (size_t)o*HWSZ + (size_t)h*512 + w;
      unsigned short gh = f2bf(gl);
      xh[base] = gh;
      xl[base] = f2bf(gl - bf2f(gh));
    }
  }
}

// ---------------- final projection (uint4 bf16 reads, 8 px/thread) ----------------
__global__ void k_final(const unsigned int* __restrict__ xh, const unsigned int* __restrict__ xl,
                        const float* __restrict__ fw, const float* __restrict__ fb,
                        float4* __restrict__ out){
  int p8 = blockIdx.x*256 + threadIdx.x;      // < HW/8 = 32768
  float b = fb[0];
  float acc[8];
  #pragma unroll
  for (int u = 0; u < 8; ++u) acc[u] = b;
  #pragma unroll 4
  for (int i = 0; i < CC; ++i){
    uint4 vh = ((const uint4*)xh)[(size_t)i*32768 + p8];
    uint4 vl = ((const uint4*)xl)[(size_t)i*32768 + p8];
    float wv = fw[i];
    acc[0] = fmaf(wv, bfu_lo(vh.x)+bfu_lo(vl.x), acc[0]);
    acc[1] = fmaf(wv, bfu_hi(vh.x)+bfu_hi(vl.x), acc[1]);
    acc[2] = fmaf(wv, bfu_lo(vh.y)+bfu_lo(vl.y), acc[2]);
    acc[3] = fmaf(wv, bfu_hi(vh.y)+bfu_hi(vl.y), acc[3]);
    acc[4] = fmaf(wv, bfu_lo(vh.z)+bfu_lo(vl.z), acc[4]);
    acc[5] = fmaf(wv, bfu_hi(vh.z)+bfu_hi(vl.z), acc[5]);
    acc[6] = fmaf(wv, bfu_lo(vh.w)+bfu_lo(vl.w), acc[6]);
    acc[7] = fmaf(wv, bfu_hi(vh.w)+bfu_hi(vl.w), acc[7]);
  }
  out[p8*2]   = make_float4(acc[0], acc[1], acc[2], acc[3]);
  out[p8*2+1] = make_float4(acc[4], acc[5], acc[6], acc[7]);
}

extern "C" void kernel_launch(void* const* d_in, const int* in_sizes, int n_in,
                              void* d_out, int out_size, void* d_ws, size_t ws_size,
                              hipStream_t stream) {
  const float* q       = (const float*)d_in[0];
  const float* proj_w  = (const float*)d_in[1];
  const float* proj_b  = (const float*)d_in[2];
  const float* spec_wr = (const float*)d_in[3];
  const float* spec_wi = (const float*)d_in[4];
  const float* w_w     = (const float*)d_in[5];
  const float* w_b     = (const float*)d_in[6];
  const float* final_w = (const float*)d_in[7];
  const float* final_b = (const float*)d_in[8];
  float* out = (float*)d_out;

  // Workspace (bytes, end-exclusive):
  //   ctab   [       0,   32768)
  //   stab   [   32768,   65536)
  //   trigBh [   65536,   98304)   trigBl [   98304,  131072)
  //   X1     [  131072,  4325376)  4 MiB; Thi [131072,2228224) Tlo [2228224,4325376) alias
  //          (dfth is the last X1 reader each layer; idfth then overwrites as T)
  //   Xfp    [ 4325376,  4587520)  256 KiB (2 h-chunks x 64 x 256 float2)
  //   Y      [ 4587520,  4718592)  128 KiB
  //   xh     [ 4718592, 38273024)  32 MiB  (bf16 hi, [c][h][w])
  //   xl     [38273024, 71827456)  32 MiB  (bf16 residual)
  //   Whi    [71827456, 71860224)  Wlo [71860224, 71892992)
  //   trigTh [71892992, 71925760)  trigTl [71925760, 71958528)   total ~68.6 MiB
  char* ws = (char*)d_ws;
  float*  ctab = (float*) (ws + 0);
  float*  stab = (float*) (ws + 32768);
  unsigned short* trigBh = (unsigned short*)(ws + 65536);
  unsigned short* trigBl = (unsigned short*)(ws + 98304);
  float2* X1   = (float2*)(ws + 131072);
  unsigned short* Thi = (unsigned short*)(ws + 131072);
  unsigned short* Tlo = (unsigned short*)(ws + 2228224);
  float2* Xfp  = (float2*)(ws + 4325376);
  float2* Y    = (float2*)(ws + 4587520);
  unsigned short* xh = (unsigned short*)(ws + 4718592);
  unsigned short* xl = (unsigned short*)(ws + 38273024);
  unsigned short* Whi = (unsigned short*)(ws + 71827456);
  unsigned short* Wlo = (unsigned short*)(ws + 71860224);
  unsigned short* trigTh = (unsigned short*)(ws + 71892992);
  unsigned short* trigTl = (unsigned short*)(ws + 71925760);

  k_init<<<96, 256, 0, stream>>>(w_w, ctab, stab, trigBh, trigBl, trigTh, trigTl, Whi, Wlo);
  k_lift<<<16384, 256, 0, stream>>>((const float4*)q, proj_w, proj_b,
                                    (unsigned int*)xh, (unsigned int*)xl);

  for (int d = 0; d < DEPTH; ++d){
    k_dftw<<<512, 256, 0, stream>>>((const unsigned int*)xh, (const unsigned int*)xl,
                                    trigTh, trigTl, (float*)X1);
    k_dfth<<<dim3(64,2), 256, 0, stream>>>(X1, ctab, stab, Xfp);
    k_contract<<<dim3(64,4), 64, 0, stream>>>(Xfp, spec_wr + (size_t)d*1048576,
                                              spec_wi + (size_t)d*1048576, Y);
    k_idfth<<<2048, 256, 0, stream>>>(Y, ctab, stab, Thi, Tlo);
    k_combine<<<dim3(8,512), 256, 0, stream>>>(xh, xl, Whi + d*4096, Wlo + d*4096,
                                               Thi, Tlo, trigBh, trigBl, w_b + d*64);
  }
  k_final<<<128, 256, 0, stream>>>((const unsigned int*)xh, (const unsigned int*)xl,
                                   final_w, final_b, (float4*)out);
}

// Round 10
// 425.608 us; speedup vs baseline: 1.0504x; 1.0504x over previous
//
#include <hip/hip_runtime.h>
#include <cmath>

#define CC 64
#define HH 512
#define WWID 512
#define HWSZ (HH*WWID)
#define DEPTH 4

typedef __attribute__((ext_vector_type(8))) short short8;
typedef __attribute__((ext_vector_type(4))) float floatx4;

__device__ inline unsigned short f2bf(float f){
  unsigned int u = __float_as_uint(f);
  u += 0x7FFF + ((u >> 16) & 1);          // round-to-nearest-even
  return (unsigned short)(u >> 16);
}
__device__ inline float bf2f(unsigned short h){
  return __uint_as_float(((unsigned int)h) << 16);
}
// packed x word: bits[31:16] = bf16 hi, bits[15:0] = bf16 residual lo
__device__ inline unsigned int packsplit(float v){
  unsigned short h = f2bf(v);
  unsigned short l = f2bf(v - bf2f(h));
  return ((unsigned int)h << 16) | l;
}
__device__ inline float unpackval(unsigned int u){   // hi + lo reconstruction
  return __uint_as_float(u & 0xFFFF0000u) + __uint_as_float(u << 16);
}

// ---------------- init ----------------
__global__ void k_init(const float* __restrict__ ww,
                       float* __restrict__ ctab, float* __restrict__ stab,
                       unsigned short* __restrict__ trigBh, unsigned short* __restrict__ trigBl,
                       unsigned short* __restrict__ trigTh, unsigned short* __restrict__ trigTl,
                       unsigned short* __restrict__ Whi, unsigned short* __restrict__ Wlo){
  int idx = blockIdx.x*256 + threadIdx.x;
  if (idx < 8192){
    int pos = idx >> 4, k = idx & 15;
    int r = (pos * k) & 511;
    double ang = (2.0 * 3.14159265358979323846 / 512.0) * (double)r;
    float c = (float)cos(ang), s = (float)sin(ang);
    ctab[idx] = c;  stab[idx] = s;
    unsigned short ch = f2bf(c), sh = f2bf(s);
    unsigned short cl = f2bf(c - bf2f(ch)), sl = f2bf(s - bf2f(sh));
    trigBh[pos*32 + 2*k]     = ch;  trigBl[pos*32 + 2*k]     = cl;
    trigBh[pos*32 + 2*k + 1] = sh;  trigBl[pos*32 + 2*k + 1] = sl;
    trigTh[(2*k)*512 + pos]   = ch;  trigTl[(2*k)*512 + pos]   = cl;
    trigTh[(2*k+1)*512 + pos] = sh;  trigTl[(2*k+1)*512 + pos] = sl;
  } else {
    int t = idx - 8192;                   // < 4*64*64, flat [d][o][i]
    float v = ww[t];
    unsigned short h = f2bf(v);
    Whi[t] = h;  Wlo[t] = f2bf(v - bf2f(h));
  }
}

// ---------------- lift: packed split-bf16 store ----------------
__global__ void k_lift(const float4* __restrict__ q, const float* __restrict__ pw,
                       const float* __restrict__ pb, unsigned int* __restrict__ xp){
  int idx = blockIdx.x*256 + threadIdx.x;     // < 64*HW/4
  int c = idx >> 16, p = idx & (HWSZ/4 - 1);
  float4 v = q[p];
  float a = pw[c], b = pb[c];
  uint4 U;
  U.x = packsplit(fmaf(a, v.x, b));
  U.y = packsplit(fmaf(a, v.y, b));
  U.z = packsplit(fmaf(a, v.z, b));
  U.w = packsplit(fmaf(a, v.w, b));
  ((uint4*)xp)[c*65536 + p] = U;
}

// ---------------- A: DFT along w as split-bf16 MFMA GEMM (packed x: bitop unpack staging) ----------------
#define APITCH 136   // shorts/row: 272 B rows, 16B-aligned; 68-dword stride -> 2-way bank alias (free)
__global__ __launch_bounds__(256) void k_dftw(
    const unsigned int* __restrict__ xp,
    const unsigned short* __restrict__ trigTh, const unsigned short* __restrict__ trigTl,
    float* __restrict__ X1f){
  __shared__ unsigned short Ahs[64*APITCH], Als[64*APITCH];
  __shared__ unsigned short Bhs[32*APITCH], Bls[32*APITCH];
  int row0 = blockIdx.x * 64;                 // 64 (c,h) rows per block
  int t = threadIdx.x;
  int g = t >> 6, lm = t & 15, lq = (t >> 4) & 3;

  floatx4 acc[2] = {{0.f,0.f,0.f,0.f},{0.f,0.f,0.f,0.f}};

  for (int kc = 0; kc < 4; ++kc){             // K chunks of 128
    {                                         // stage A: uint4 loads, 2-bitop/dword unpack
      int r = t >> 2, q = t & 3;
      const uint4* src = (const uint4*)(xp + (size_t)(row0 + r)*512 + kc*128 + q*32);
      uint4* dh = (uint4*)&Ahs[r*APITCH + q*32];
      uint4* dl = (uint4*)&Als[r*APITCH + q*32];
      #pragma unroll
      for (int u = 0; u < 4; ++u){
        uint4 a = src[2*u], b = src[2*u+1];
        uint4 H, L;
        H.x = (a.x >> 16) | (a.y & 0xFFFF0000u);  L.x = (a.x & 0xFFFFu) | (a.y << 16);
        H.y = (a.z >> 16) | (a.w & 0xFFFF0000u);  L.y = (a.z & 0xFFFFu) | (a.w << 16);
        H.z = (b.x >> 16) | (b.y & 0xFFFF0000u);  L.z = (b.x & 0xFFFFu) | (b.y << 16);
        H.w = (b.z >> 16) | (b.w & 0xFFFF0000u);  L.w = (b.z & 0xFFFFu) | (b.w << 16);
        dh[u] = H;  dl[u] = L;
      }
    }
    {                                         // stage B: trig rows copy
      int j = t >> 3, q = t & 7;
      const unsigned int* sh = (const unsigned int*)trigTh + j*256 + kc*64 + q*8;
      const unsigned int* sl = (const unsigned int*)trigTl + j*256 + kc*64 + q*8;
      unsigned int* dh = (unsigned int*)&Bhs[j*APITCH + q*16];
      unsigned int* dl = (unsigned int*)&Bls[j*APITCH + q*16];
      #pragma unroll
      for (int u = 0; u < 8; ++u){ dh[u] = sh[u]; dl[u] = sl[u]; }
    }
    __syncthreads();
    #pragma unroll
    for (int ks = 0; ks < 4; ++ks){
      short8 ah = *(const short8*)&Ahs[(g*16 + lm)*APITCH + ks*32 + lq*8];
      short8 al = *(const short8*)&Als[(g*16 + lm)*APITCH + ks*32 + lq*8];
      #pragma unroll
      for (int nt = 0; nt < 2; ++nt){
        short8 bh = *(const short8*)&Bhs[(nt*16 + lm)*APITCH + ks*32 + lq*8];
        short8 bl = *(const short8*)&Bls[(nt*16 + lm)*APITCH + ks*32 + lq*8];
        acc[nt] = __builtin_amdgcn_mfma_f32_16x16x32_bf16(ah, bh, acc[nt], 0, 0, 0);
        acc[nt] = __builtin_amdgcn_mfma_f32_16x16x32_bf16(ah, bl, acc[nt], 0, 0, 0);
        acc[nt] = __builtin_amdgcn_mfma_f32_16x16x32_bf16(al, bh, acc[nt], 0, 0, 0);
      }
    }
    __syncthreads();
  }
  #pragma unroll
  for (int nt = 0; nt < 2; ++nt){
    int j = nt*16 + lm;
    float sgn = (j & 1) ? -1.f : 1.f;
    #pragma unroll
    for (int rg = 0; rg < 4; ++rg){
      int m = g*16 + lq*4 + rg;
      X1f[(size_t)(row0 + m)*32 + j] = sgn * acc[nt][rg];
    }
  }
}

// ---------------- B1: partial DFT along h (16 chunks of 32) — R8-measured shape ----------------
__global__ void k_dfth(const float2* __restrict__ X1, const float* __restrict__ ct,
                       const float* __restrict__ st, float2* __restrict__ Xfp){
  int i = blockIdx.x, ch = blockIdx.y;
  int m = threadIdx.x >> 4, n = threadIdx.x & 15;
  float ar = 0.f, ai = 0.f;
  int h0 = ch * 32;
  #pragma unroll 8
  for (int hh = 0; hh < 32; ++hh){
    int h = h0 + hh;
    float2 v = X1[(i*512 + h)*16 + n];
    float c = ct[h*16 + m], s = st[h*16 + m];
    ar += v.x*c + v.y*s;
    ai += v.y*c - v.x*s;
  }
  Xfp[(ch*64 + i)*256 + threadIdx.x] = make_float2(ar, ai);
}

// ---------------- B1b: reduce h-chunk partials ----------------
__global__ void k_redXf(const float2* __restrict__ Xfp, float2* __restrict__ Xf){
  int i = blockIdx.x, mn = threadIdx.x;
  float ar = 0.f, ai = 0.f;
  #pragma unroll
  for (int ch = 0; ch < 16; ++ch){
    float2 v = Xfp[(ch*64 + i)*256 + mn];
    ar += v.x; ai += v.y;
  }
  Xf[i*256 + mn] = make_float2(ar, ai);
}

// ---------------- B2: mode contraction, i-chunked, mn-split — R8-measured shape ----------------
__global__ void k_contract(const float2* __restrict__ Xf,
                           const float* __restrict__ wr, const float* __restrict__ wi,
                           float2* __restrict__ Yp){
  int o = blockIdx.x, ic = blockIdx.y;
  int mn = blockIdx.z*64 + threadIdx.x;
  float ar = 0.f, ai = 0.f;
  int i0 = ic * 16;
  #pragma unroll
  for (int ii = 0; ii < 16; ++ii){
    int i = i0 + ii;
    float2 xf = Xf[i*256 + mn];
    float wrv = wr[(i*64 + o)*256 + mn];
    float wiv = wi[(i*64 + o)*256 + mn];
    ar += xf.x*wrv - xf.y*wiv;
    ai += xf.x*wiv + xf.y*wrv;
  }
  const float sc = 1.f/262144.f;
  Yp[(ic*64 + o)*256 + mn] = make_float2(ar*sc, ai*sc);
}

// ---------------- B3: iDFT along h -> T split bf16, sign-folded, dword stores ----------------
__global__ void k_idfth(const float2* __restrict__ Yp, const float* __restrict__ ct,
                        const float* __restrict__ st,
                        unsigned int* __restrict__ Thi, unsigned int* __restrict__ Tlo){
  int idx = blockIdx.x*256 + threadIdx.x;     // (h*64+o)*16+n
  int n = idx & 15, o = (idx >> 4) & 63, h = idx >> 10;
  float ar = 0.f, ai = 0.f;
  #pragma unroll
  for (int m = 0; m < 16; ++m){
    float yr = 0.f, yi = 0.f;
    #pragma unroll
    for (int jc = 0; jc < 4; ++jc){
      float2 y = Yp[((jc<<6) + o)*256 + (m<<4) + n];
      yr += y.x; yi += y.y;
    }
    float c = ct[h*16 + m], s = st[h*16 + m];
    ar += yr*c - yi*s;
    ai += yr*s + yi*c;
  }
  float tr = ar, ts = -ai;
  unsigned short rh = f2bf(tr), sh = f2bf(ts);
  // element order in T rows: [2n]=Tr, [2n+1]=-Ti -> dword = Tr | (-Ti << 16)
  Thi[idx] = (unsigned int)rh | ((unsigned int)sh << 16);
  unsigned short rl = f2bf(tr - bf2f(rh)), slr = f2bf(ts - bf2f(sh));
  Tlo[idx] = (unsigned int)rl | ((unsigned int)slr << 16);
}

// ---------------- C: combine GEMM (K=96), split-bf16 3-pass, packed x ----------------
#define PITCH 104   // 208 B rows: 16B-aligned, 2-way bank alias (free)
__global__ __launch_bounds__(256) void k_combine(
    unsigned int* __restrict__ xp,
    const unsigned short* __restrict__ Whid, const unsigned short* __restrict__ Wlod,
    const unsigned int* __restrict__ Thi,  const unsigned int* __restrict__ Tlo,
    const unsigned short* __restrict__ trigBh, const unsigned short* __restrict__ trigBl,
    const float* __restrict__ wb)
{
  __shared__ unsigned short Ah[64*PITCH], Al[64*PITCH];   // rows o, k 0..95
  __shared__ unsigned short Bh[64*PITCH], Bl[64*PITCH];   // rows w(pixel), k 0..95
  int h  = blockIdx.y;
  int w0 = blockIdx.x * 64;
  int t  = threadIdx.x;

  {   // B x-part: dword loads (256 B/wave, as R8), 2-bitop unpack
    int wl = t & 63, ig = t >> 6;
    const unsigned int* xb = xp + (size_t)h*512 + w0 + wl;
    #pragma unroll
    for (int ii = 0; ii < 16; ii += 2){
      int i0 = ig*16 + ii;
      unsigned int a0 = xb[(size_t)i0*HWSZ];
      unsigned int a1 = xb[(size_t)(i0+1)*HWSZ];
      *(unsigned int*)&Bh[wl*PITCH + i0] = (a0 >> 16) | (a1 & 0xFFFF0000u);
      *(unsigned int*)&Bl[wl*PITCH + i0] = (a0 & 0xFFFFu) | (a1 << 16);
    }
  }
  {   // B trig-part: rows w, k=64..95
    int row = t >> 2, qq = t & 3;
    const unsigned int* sh = (const unsigned int*)trigBh + (size_t)(w0+row)*16 + qq*4;
    const unsigned int* sl = (const unsigned int*)trigBl + (size_t)(w0+row)*16 + qq*4;
    unsigned int* dh = (unsigned int*)&Bh[row*PITCH + 64] + qq*4;
    unsigned int* dl = (unsigned int*)&Bl[row*PITCH + 64] + qq*4;
    #pragma unroll
    for (int u = 0; u < 4; ++u){ dh[u] = sh[u]; dl[u] = sl[u]; }
  }
  {   // A W-part: rows o, k=0..63
    int o = t >> 2, q8 = t & 3;
    const unsigned int* sh = (const unsigned int*)Whid + o*32 + q8*8;
    const unsigned int* sl = (const unsigned int*)Wlod + o*32 + q8*8;
    unsigned int* dh = (unsigned int*)&Ah[o*PITCH] + q8*8;
    unsigned int* dl = (unsigned int*)&Al[o*PITCH] + q8*8;
    #pragma unroll
    for (int u = 0; u < 8; ++u){ dh[u] = sh[u]; dl[u] = sl[u]; }
  }
  {   // A T-part: rows o, k=64..95
    int o = t >> 2, q4 = t & 3;
    const unsigned int* sh = Thi + (size_t)h*1024 + o*16 + q4*4;
    const unsigned int* sl = Tlo + (size_t)h*1024 + o*16 + q4*4;
    unsigned int* dh = (unsigned int*)&Ah[o*PITCH + 64] + q4*4;
    unsigned int* dl = (unsigned int*)&Al[o*PITCH + 64] + q4*4;
    #pragma unroll
    for (int u = 0; u < 4; ++u){ dh[u] = sh[u]; dl[u] = sl[u]; }
  }
  __syncthreads();

  int g  = t >> 6;          // wave -> m-tile (o-rows g*16..+15)
  int lm = t & 15;
  int lq = (t >> 4) & 3;

  floatx4 acc[4] = {{0.f,0.f,0.f,0.f},{0.f,0.f,0.f,0.f},{0.f,0.f,0.f,0.f},{0.f,0.f,0.f,0.f}};

  #pragma unroll
  for (int ks = 0; ks < 3; ++ks){
    short8 af = *(const short8*)&Ah[(g*16 + lm)*PITCH + ks*32 + lq*8];
    short8 al = *(const short8*)&Al[(g*16 + lm)*PITCH + ks*32 + lq*8];
    #pragma unroll
    for (int nt = 0; nt < 4; ++nt){
      short8 bf = *(const short8*)&Bh[(nt*16 + lm)*PITCH + ks*32 + lq*8];
      short8 bl = *(const short8*)&Bl[(nt*16 + lm)*PITCH + ks*32 + lq*8];
      acc[nt] = __builtin_amdgcn_mfma_f32_16x16x32_bf16(af, bf, acc[nt], 0, 0, 0);
      acc[nt] = __builtin_amdgcn_mfma_f32_16x16x32_bf16(af, bl, acc[nt], 0, 0, 0);
      acc[nt] = __builtin_amdgcn_mfma_f32_16x16x32_bf16(al, bf, acc[nt], 0, 0, 0);
    }
  }

  // epilogue: bias + tanh-gelu + one packed dword store per (o,w)
  #pragma unroll
  for (int nt = 0; nt < 4; ++nt){
    int w = w0 + nt*16 + lm;
    #pragma unroll
    for (int rg = 0; rg < 4; ++rg){
      int o = g*16 + lq*4 + rg;
      float u = acc[nt][rg] + wb[o];
      float z = 0.7978845608028654f * fmaf(0.044715f, u*u*u, u);
      float e = __expf(2.f*z);
      float gl = u - __fdividef(u, e + 1.f);
      xp[(size_t)o*HWSZ + (size_t)h*512 + w] = packsplit(gl);
    }
  }
}

// ---------------- final projection (uint4 packed reads, 8 px/thread) ----------------
__global__ void k_final(const unsigned int* __restrict__ xp,
                        const float* __restrict__ fw, const float* __restrict__ fb,
                        float4* __restrict__ out){
  int p8 = blockIdx.x*256 + threadIdx.x;      // < HW/8 = 32768
  float b = fb[0];
  float acc[8];
  #pragma unroll
  for (int u = 0; u < 8; ++u) acc[u] = b;
  #pragma unroll 4
  for (int i = 0; i < CC; ++i){
    uint4 v0 = ((const uint4*)xp)[(size_t)i*65536 + p8*2];
    uint4 v1 = ((const uint4*)xp)[(size_t)i*65536 + p8*2 + 1];
    float wv = fw[i];
    acc[0] = fmaf(wv, unpackval(v0.x), acc[0]);
    acc[1] = fmaf(wv, unpackval(v0.y), acc[1]);
    acc[2] = fmaf(wv, unpackval(v0.z), acc[2]);
    acc[3] = fmaf(wv, unpackval(v0.w), acc[3]);
    acc[4] = fmaf(wv, unpackval(v1.x), acc[4]);
    acc[5] = fmaf(wv, unpackval(v1.y), acc[5]);
    acc[6] = fmaf(wv, unpackval(v1.z), acc[6]);
    acc[7] = fmaf(wv, unpackval(v1.w), acc[7]);
  }
  out[p8*2]   = make_float4(acc[0], acc[1], acc[2], acc[3]);
  out[p8*2+1] = make_float4(acc[4], acc[5], acc[6], acc[7]);
}

extern "C" void kernel_launch(void* const* d_in, const int* in_sizes, int n_in,
                              void* d_out, int out_size, void* d_ws, size_t ws_size,
                              hipStream_t stream) {
  const float* q       = (const float*)d_in[0];
  const float* proj_w  = (const float*)d_in[1];
  const float* proj_b  = (const float*)d_in[2];
  const float* spec_wr = (const float*)d_in[3];
  const float* spec_wi = (const float*)d_in[4];
  const float* w_w     = (const float*)d_in[5];
  const float* w_b     = (const float*)d_in[6];
  const float* final_w = (const float*)d_in[7];
  const float* final_b = (const float*)d_in[8];
  float* out = (float*)d_out;

  // Workspace (bytes, end-exclusive) — R8-proven layout, x now packed uint32:
  //   ctab   [       0,   32768)
  //   stab   [   32768,   65536)
  //   trigBh [   65536,   98304)   trigBl [   98304,  131072)
  //   X1     [  131072,  4325376)  4 MiB; Thi [131072,2228224) Tlo [2228224,4325376) alias
  //   Xfp    [ 4325376,  6422528)  2 MiB (16 h-chunks)
  //   Xf     [ 6422528,  6553600)  128 KiB
  //   Yp     [ 6553600,  7077888)  512 KiB (4 i-chunks)
  //   xp     [ 7077888, 74186752)  64 MiB (packed hi|lo per element)
  //   Whi    [74186752, 74219520)  Wlo [74219520, 74252288)
  //   trigTh [74252288, 74285056)  trigTl [74285056, 74317824)   total ~74.3 MiB
  char* ws = (char*)d_ws;
  float*  ctab = (float*) (ws + 0);
  float*  stab = (float*) (ws + 32768);
  unsigned short* trigBh = (unsigned short*)(ws + 65536);
  unsigned short* trigBl = (unsigned short*)(ws + 98304);
  float2* X1   = (float2*)(ws + 131072);
  unsigned int* Thi = (unsigned int*)(ws + 131072);
  unsigned int* Tlo = (unsigned int*)(ws + 2228224);
  float2* Xfp  = (float2*)(ws + 4325376);
  float2* Xf   = (float2*)(ws + 6422528);
  float2* Yp   = (float2*)(ws + 6553600);
  unsigned int* xp = (unsigned int*)(ws + 7077888);
  unsigned short* Whi = (unsigned short*)(ws + 74186752);
  unsigned short* Wlo = (unsigned short*)(ws + 74219520);
  unsigned short* trigTh = (unsigned short*)(ws + 74252288);
  unsigned short* trigTl = (unsigned short*)(ws + 74285056);

  k_init<<<96, 256, 0, stream>>>(w_w, ctab, stab, trigBh, trigBl, trigTh, trigTl, Whi, Wlo);
  k_lift<<<16384, 256, 0, stream>>>((const float4*)q, proj_w, proj_b, xp);

  for (int d = 0; d < DEPTH; ++d){
    k_dftw<<<512, 256, 0, stream>>>(xp, trigTh, trigTl, (float*)X1);
    k_dfth<<<dim3(64,16), 256, 0, stream>>>(X1, ctab, stab, Xfp);
    k_redXf<<<64, 256, 0, stream>>>(Xfp, Xf);
    k_contract<<<dim3(64,4,4), 64, 0, stream>>>(Xf, spec_wr + (size_t)d*1048576,
                                                spec_wi + (size_t)d*1048576, Yp);
    k_idfth<<<2048, 256, 0, stream>>>(Yp, ctab, stab, Thi, Tlo);
    k_combine<<<dim3(8,512), 256, 0, stream>>>(xp, Whi + d*4096, Wlo + d*4096,
                                               Thi, Tlo, trigBh, trigBl, w_b + d*64);
  }
  k_final<<<128, 256, 0, stream>>>(xp, final_w, final_b, (float4*)out);
}

// Round 11
// 375.185 us; speedup vs baseline: 1.1915x; 1.1344x over previous
//
#include <hip/hip_runtime.h>
#include <cmath>

#define CC 64
#define HH 512
#define WWID 512
#define HWSZ (HH*WWID)
#define DEPTH 4

typedef __attribute__((ext_vector_type(8))) short short8;
typedef __attribute__((ext_vector_type(4))) float floatx4;

__device__ inline unsigned short f2bf(float f){
  unsigned int u = __float_as_uint(f);
  u += 0x7FFF + ((u >> 16) & 1);          // round-to-nearest-even
  return (unsigned short)(u >> 16);
}
__device__ inline float bf2f(unsigned short h){
  return __uint_as_float(((unsigned int)h) << 16);
}

// ---------------- init ----------------
__global__ void k_init(const float* __restrict__ ww,
                       float* __restrict__ ctab, float* __restrict__ stab,
                       unsigned short* __restrict__ trigBh, unsigned short* __restrict__ trigBl,
                       unsigned short* __restrict__ trigTh, unsigned short* __restrict__ trigTl,
                       unsigned short* __restrict__ Whi, unsigned short* __restrict__ Wlo){
  int idx = blockIdx.x*256 + threadIdx.x;
  if (idx < 8192){
    int pos = idx >> 4, k = idx & 15;
    int r = (pos * k) & 511;
    double ang = (2.0 * 3.14159265358979323846 / 512.0) * (double)r;
    float c = (float)cos(ang), s = (float)sin(ang);
    ctab[idx] = c;  stab[idx] = s;
    unsigned short ch = f2bf(c), sh = f2bf(s);
    unsigned short cl = f2bf(c - bf2f(ch)), sl = f2bf(s - bf2f(sh));
    trigBh[pos*32 + 2*k]     = ch;  trigBl[pos*32 + 2*k]     = cl;
    trigBh[pos*32 + 2*k + 1] = sh;  trigBl[pos*32 + 2*k + 1] = sl;
    trigTh[(2*k)*512 + pos]   = ch;  trigTl[(2*k)*512 + pos]   = cl;
    trigTh[(2*k+1)*512 + pos] = sh;  trigTl[(2*k+1)*512 + pos] = sl;
  } else {
    int t = idx - 8192;                   // < 4*64*64, flat [d][o][i]
    float v = ww[t];
    unsigned short h = f2bf(v);
    Whi[t] = h;  Wlo[t] = f2bf(v - bf2f(h));
  }
}

// ---------------- lift: x[c,h,w] = proj_w[c]*q[h,w] + proj_b[c]  (fp32 x, R8) ----------------
__global__ void k_lift(const float4* __restrict__ q, const float* __restrict__ pw,
                       const float* __restrict__ pb, float4* __restrict__ x){
  int idx = blockIdx.x*256 + threadIdx.x;     // < 64*HW/4
  int c = idx >> 16, p = idx & (HWSZ/4 - 1);
  float4 v = q[p];
  float a = pw[c], b = pb[c];
  v.x = fmaf(a, v.x, b); v.y = fmaf(a, v.y, b);
  v.z = fmaf(a, v.z, b); v.w = fmaf(a, v.w, b);
  x[idx] = v;
}

// ---------------- A: DFT along w as split-bf16 MFMA GEMM (R8 body + Xf zero tail) ----------------
#define APITCH 136
__global__ __launch_bounds__(256) void k_dftw(const float* __restrict__ x,
    const unsigned short* __restrict__ trigTh, const unsigned short* __restrict__ trigTl,
    float* __restrict__ X1f, float4* __restrict__ Xfz){
  // zero Xf for the NEXT dispatch's (k_dfth) atomics — safe: consumed only after
  // the dftw->dfth dispatch boundary. 32 blocks x 256 thr x 16 B = 128 KiB.
  if (blockIdx.x < 32) Xfz[blockIdx.x*256 + threadIdx.x] = make_float4(0.f,0.f,0.f,0.f);

  __shared__ unsigned short Ahs[64*APITCH], Als[64*APITCH];
  __shared__ unsigned short Bhs[32*APITCH], Bls[32*APITCH];
  int row0 = blockIdx.x * 64;                 // 64 (c,h) rows per block
  int t = threadIdx.x;
  int g = t >> 6, lm = t & 15, lq = (t >> 4) & 3;

  floatx4 acc[2] = {{0.f,0.f,0.f,0.f},{0.f,0.f,0.f,0.f}};

  for (int kc = 0; kc < 4; ++kc){             // K chunks of 128
    {                                         // stage A: 64 rows x 128 k, fp32 -> split bf16
      int r = t >> 2, q = t & 3;
      const float4* src4 = (const float4*)(x + (size_t)(row0 + r)*512 + kc*128 + q*32);
      unsigned int* dh = (unsigned int*)&Ahs[r*APITCH + q*32];
      unsigned int* dl = (unsigned int*)&Als[r*APITCH + q*32];
      #pragma unroll
      for (int u = 0; u < 8; ++u){
        float4 v = src4[u];
        unsigned short h0 = f2bf(v.x), h1 = f2bf(v.y), h2 = f2bf(v.z), h3 = f2bf(v.w);
        dh[u*2]   = (unsigned)h0 | ((unsigned)h1 << 16);
        dh[u*2+1] = (unsigned)h2 | ((unsigned)h3 << 16);
        unsigned short g0 = f2bf(v.x - bf2f(h0)), g1 = f2bf(v.y - bf2f(h1));
        unsigned short g2 = f2bf(v.z - bf2f(h2)), g3 = f2bf(v.w - bf2f(h3));
        dl[u*2]   = (unsigned)g0 | ((unsigned)g1 << 16);
        dl[u*2+1] = (unsigned)g2 | ((unsigned)g3 << 16);
      }
    }
    {                                         // stage B: 32 rows x 128 k (bf16 copy)
      int j = t >> 3, q = t & 7;
      const unsigned int* sh = (const unsigned int*)trigTh + j*256 + kc*64 + q*8;
      const unsigned int* sl = (const unsigned int*)trigTl + j*256 + kc*64 + q*8;
      unsigned int* dh = (unsigned int*)&Bhs[j*APITCH + q*16];
      unsigned int* dl = (unsigned int*)&Bls[j*APITCH + q*16];
      #pragma unroll
      for (int u = 0; u < 8; ++u){ dh[u] = sh[u]; dl[u] = sl[u]; }
    }
    __syncthreads();
    #pragma unroll
    for (int ks = 0; ks < 4; ++ks){
      short8 ah = *(const short8*)&Ahs[(g*16 + lm)*APITCH + ks*32 + lq*8];
      short8 al = *(const short8*)&Als[(g*16 + lm)*APITCH + ks*32 + lq*8];
      #pragma unroll
      for (int nt = 0; nt < 2; ++nt){
        short8 bh = *(const short8*)&Bhs[(nt*16 + lm)*APITCH + ks*32 + lq*8];
        short8 bl = *(const short8*)&Bls[(nt*16 + lm)*APITCH + ks*32 + lq*8];
        acc[nt] = __builtin_amdgcn_mfma_f32_16x16x32_bf16(ah, bh, acc[nt], 0, 0, 0);
        acc[nt] = __builtin_amdgcn_mfma_f32_16x16x32_bf16(ah, bl, acc[nt], 0, 0, 0);
        acc[nt] = __builtin_amdgcn_mfma_f32_16x16x32_bf16(al, bh, acc[nt], 0, 0, 0);
      }
    }
    __syncthreads();
  }
  #pragma unroll
  for (int nt = 0; nt < 2; ++nt){
    int j = nt*16 + lm;
    float sgn = (j & 1) ? -1.f : 1.f;
    #pragma unroll
    for (int rg = 0; rg < 4; ++rg){
      int m = g*16 + lq*4 + rg;
      X1f[(size_t)(row0 + m)*32 + j] = sgn * acc[nt][rg];
    }
  }
}

// ---------------- B1: partial DFT along h (64x16 blocks), atomicAdd into Xf; zero Y tail ----------------
__global__ void k_dfth(const float2* __restrict__ X1, const float* __restrict__ ct,
                       const float* __restrict__ st, float* __restrict__ Xfa,
                       float4* __restrict__ Yz){
  // zero Y for k_contract's atomics — consumed after the dfth->contract boundary.
  int flat = blockIdx.y*64 + blockIdx.x;
  if (flat < 32) Yz[flat*256 + threadIdx.x] = make_float4(0.f,0.f,0.f,0.f);

  int i = blockIdx.x, ch = blockIdx.y;
  int m = threadIdx.x >> 4, n = threadIdx.x & 15;
  float ar = 0.f, ai = 0.f;
  int h0 = ch * 32;
  #pragma unroll 8
  for (int hh = 0; hh < 32; ++hh){
    int h = h0 + hh;
    float2 v = X1[(i*512 + h)*16 + n];
    float c = ct[h*16 + m], s = st[h*16 + m];
    ar += v.x*c + v.y*s;
    ai += v.y*c - v.x*s;
  }
  atomicAdd(&Xfa[(i*256 + threadIdx.x)*2],     ar);
  atomicAdd(&Xfa[(i*256 + threadIdx.x)*2 + 1], ai);
}

// ---------------- B2: mode contraction, i-chunked, mn-split; atomicAdd into Y ----------------
__global__ void k_contract(const float2* __restrict__ Xf,
                           const float* __restrict__ wr, const float* __restrict__ wi,
                           float* __restrict__ Ya){
  int o = blockIdx.x, ic = blockIdx.y;
  int mn = blockIdx.z*64 + threadIdx.x;
  float ar = 0.f, ai = 0.f;
  int i0 = ic * 16;
  #pragma unroll
  for (int ii = 0; ii < 16; ++ii){
    int i = i0 + ii;
    float2 xf = Xf[i*256 + mn];
    float wrv = wr[(i*64 + o)*256 + mn];
    float wiv = wi[(i*64 + o)*256 + mn];
    ar += xf.x*wrv - xf.y*wiv;
    ai += xf.x*wiv + xf.y*wrv;
  }
  const float sc = 1.f/262144.f;
  atomicAdd(&Ya[(o*256 + mn)*2],     ar*sc);
  atomicAdd(&Ya[(o*256 + mn)*2 + 1], ai*sc);
}

// ---------------- B3: iDFT along h -> T split bf16, sign-folded, dword stores ----------------
__global__ void k_idfth(const float2* __restrict__ Y, const float* __restrict__ ct,
                        const float* __restrict__ st,
                        unsigned int* __restrict__ Thi, unsigned int* __restrict__ Tlo){
  int idx = blockIdx.x*256 + threadIdx.x;     // (h*64+o)*16+n
  int n = idx & 15, o = (idx >> 4) & 63, h = idx >> 10;
  float ar = 0.f, ai = 0.f;
  #pragma unroll
  for (int m = 0; m < 16; ++m){
    float2 y = Y[(o<<8) + (m<<4) + n];
    float c = ct[h*16 + m], s = st[h*16 + m];
    ar += y.x*c - y.y*s;
    ai += y.x*s + y.y*c;
  }
  float tr = ar, ts = -ai;
  unsigned short rh = f2bf(tr), sh = f2bf(ts);
  Thi[idx] = (unsigned int)rh | ((unsigned int)sh << 16);   // [2n]=Tr low, [2n+1]=-Ti high
  unsigned short rl = f2bf(tr - bf2f(rh)), slr = f2bf(ts - bf2f(sh));
  Tlo[idx] = (unsigned int)rl | ((unsigned int)slr << 16);
}

// ---------------- C: combine GEMM (K=96), split-bf16 3-pass, fp32 x (R8 verbatim) ----------------
#define PITCH 104
__global__ __launch_bounds__(256) void k_combine(
    const float* __restrict__ x,
    const unsigned short* __restrict__ Whid, const unsigned short* __restrict__ Wlod,
    const unsigned int* __restrict__ Thi,  const unsigned int* __restrict__ Tlo,
    const unsigned short* __restrict__ trigBh, const unsigned short* __restrict__ trigBl,
    const float* __restrict__ wb, float* __restrict__ xo)
{
  __shared__ unsigned short Ah[64*PITCH], Al[64*PITCH];   // rows o, k 0..95
  __shared__ unsigned short Bh[64*PITCH], Bl[64*PITCH];   // rows w(pixel), k 0..95
  int h  = blockIdx.y;
  int w0 = blockIdx.x * 64;
  int t  = threadIdx.x;

  {   // B x-part: coalesced fp32 reads, f2bf split, packed b32 LDS writes
    int wl = t & 63, ig = t >> 6;
    const float* xb = x + (size_t)h*512 + w0 + wl;
    #pragma unroll
    for (int ii = 0; ii < 16; ii += 2){
      int i0 = ig*16 + ii;
      float v0 = xb[(size_t)i0*HWSZ];
      float v1 = xb[(size_t)(i0+1)*HWSZ];
      unsigned short h0 = f2bf(v0), h1 = f2bf(v1);
      unsigned short g0 = f2bf(v0 - bf2f(h0)), g1 = f2bf(v1 - bf2f(h1));
      *(unsigned int*)&Bh[wl*PITCH + i0] = (unsigned int)h0 | ((unsigned int)h1 << 16);
      *(unsigned int*)&Bl[wl*PITCH + i0] = (unsigned int)g0 | ((unsigned int)g1 << 16);
    }
  }
  {   // B trig-part: rows w, k=64..95
    int row = t >> 2, qq = t & 3;
    const unsigned int* sh = (const unsigned int*)trigBh + (size_t)(w0+row)*16 + qq*4;
    const unsigned int* sl = (const unsigned int*)trigBl + (size_t)(w0+row)*16 + qq*4;
    unsigned int* dh = (unsigned int*)&Bh[row*PITCH + 64] + qq*4;
    unsigned int* dl = (unsigned int*)&Bl[row*PITCH + 64] + qq*4;
    #pragma unroll
    for (int u = 0; u < 4; ++u){ dh[u] = sh[u]; dl[u] = sl[u]; }
  }
  {   // A W-part: rows o, k=0..63
    int o = t >> 2, q8 = t & 3;
    const unsigned int* sh = (const unsigned int*)Whid + o*32 + q8*8;
    const unsigned int* sl = (const unsigned int*)Wlod + o*32 + q8*8;
    unsigned int* dh = (unsigned int*)&Ah[o*PITCH] + q8*8;
    unsigned int* dl = (unsigned int*)&Al[o*PITCH] + q8*8;
    #pragma unroll
    for (int u = 0; u < 8; ++u){ dh[u] = sh[u]; dl[u] = sl[u]; }
  }
  {   // A T-part: rows o, k=64..95
    int o = t >> 2, q4 = t & 3;
    const unsigned int* sh = Thi + (size_t)h*1024 + o*16 + q4*4;
    const unsigned int* sl = Tlo + (size_t)h*1024 + o*16 + q4*4;
    unsigned int* dh = (unsigned int*)&Ah[o*PITCH + 64] + q4*4;
    unsigned int* dl = (unsigned int*)&Al[o*PITCH + 64] + q4*4;
    #pragma unroll
    for (int u = 0; u < 4; ++u){ dh[u] = sh[u]; dl[u] = sl[u]; }
  }
  __syncthreads();

  int g  = t >> 6;          // wave -> m-tile (o-rows g*16..+15)
  int lm = t & 15;
  int lq = (t >> 4) & 3;

  floatx4 acc[4] = {{0.f,0.f,0.f,0.f},{0.f,0.f,0.f,0.f},{0.f,0.f,0.f,0.f},{0.f,0.f,0.f,0.f}};

  #pragma unroll
  for (int ks = 0; ks < 3; ++ks){
    short8 af = *(const short8*)&Ah[(g*16 + lm)*PITCH + ks*32 + lq*8];
    short8 al = *(const short8*)&Al[(g*16 + lm)*PITCH + ks*32 + lq*8];
    #pragma unroll
    for (int nt = 0; nt < 4; ++nt){
      short8 bf = *(const short8*)&Bh[(nt*16 + lm)*PITCH + ks*32 + lq*8];
      short8 bl = *(const short8*)&Bl[(nt*16 + lm)*PITCH + ks*32 + lq*8];
      acc[nt] = __builtin_amdgcn_mfma_f32_16x16x32_bf16(af, bf, acc[nt], 0, 0, 0);
      acc[nt] = __builtin_amdgcn_mfma_f32_16x16x32_bf16(af, bl, acc[nt], 0, 0, 0);
      acc[nt] = __builtin_amdgcn_mfma_f32_16x16x32_bf16(al, bf, acc[nt], 0, 0, 0);
    }
  }

  // epilogue: bias + tanh-gelu + fp32 in-place store
  #pragma unroll
  for (int nt = 0; nt < 4; ++nt){
    int w = w0 + nt*16 + lm;
    #pragma unroll
    for (int rg = 0; rg < 4; ++rg){
      int o = g*16 + lq*4 + rg;
      float u = acc[nt][rg] + wb[o];
      float z = 0.7978845608028654f * fmaf(0.044715f, u*u*u, u);
      float e = __expf(2.f*z);
      float gl = u - __fdividef(u, e + 1.f);
      xo[(size_t)o*HWSZ + (size_t)h*512 + w] = gl;
    }
  }
}

// ---------------- final projection (float4, R8) ----------------
__global__ void k_final(const float* __restrict__ x, const float* __restrict__ fw,
                        const float* __restrict__ fb, float4* __restrict__ out){
  int p4 = blockIdx.x*256 + threadIdx.x;      // < HW/4 = 65536
  float b = fb[0];
  float4 acc = make_float4(b, b, b, b);
  #pragma unroll
  for (int i = 0; i < CC; ++i){
    float4 v = *(const float4*)(x + (size_t)i*HWSZ + (size_t)p4*4);
    float wv = fw[i];
    acc.x = fmaf(wv, v.x, acc.x); acc.y = fmaf(wv, v.y, acc.y);
    acc.z = fmaf(wv, v.z, acc.z); acc.w = fmaf(wv, v.w, acc.w);
  }
  out[p4] = acc;
}

extern "C" void kernel_launch(void* const* d_in, const int* in_sizes, int n_in,
                              void* d_out, int out_size, void* d_ws, size_t ws_size,
                              hipStream_t stream) {
  const float* q       = (const float*)d_in[0];
  const float* proj_w  = (const float*)d_in[1];
  const float* proj_b  = (const float*)d_in[2];
  const float* spec_wr = (const float*)d_in[3];
  const float* spec_wi = (const float*)d_in[4];
  const float* w_w     = (const float*)d_in[5];
  const float* w_b     = (const float*)d_in[6];
  const float* final_w = (const float*)d_in[7];
  const float* final_b = (const float*)d_in[8];
  float* out = (float*)d_out;

  // Workspace (bytes, end-exclusive):
  //   ctab   [       0,   32768)
  //   stab   [   32768,   65536)
  //   trigBh [   65536,   98304)   trigBl [   98304,  131072)
  //   X1     [  131072,  4325376)  4 MiB; Thi [131072,2228224) Tlo [2228224,4325376) alias
  //          (dfth is the last X1 reader each layer; idfth then overwrites as T)
  //   Xf     [ 4325376,  4456448)  128 KiB (dfth atomics; zeroed by dftw tail)
  //   Y      [ 4456448,  4587520)  128 KiB (contract atomics; zeroed by dfth tail)
  //   x      [ 4587520, 71696384)  64 MiB fp32
  //   Whi    [71696384, 71729152)  Wlo [71729152, 71761920)
  //   trigTh [71761920, 71794688)  trigTl [71794688, 71827456)   total ~68.5 MiB
  char* ws = (char*)d_ws;
  float*  ctab = (float*) (ws + 0);
  float*  stab = (float*) (ws + 32768);
  unsigned short* trigBh = (unsigned short*)(ws + 65536);
  unsigned short* trigBl = (unsigned short*)(ws + 98304);
  float2* X1   = (float2*)(ws + 131072);
  unsigned int* Thi = (unsigned int*)(ws + 131072);
  unsigned int* Tlo = (unsigned int*)(ws + 2228224);
  float*  Xf   = (float*) (ws + 4325376);
  float*  Y    = (float*) (ws + 4456448);
  float*  x    = (float*) (ws + 4587520);
  unsigned short* Whi = (unsigned short*)(ws + 71696384);
  unsigned short* Wlo = (unsigned short*)(ws + 71729152);
  unsigned short* trigTh = (unsigned short*)(ws + 71761920);
  unsigned short* trigTl = (unsigned short*)(ws + 71794688);

  k_init<<<96, 256, 0, stream>>>(w_w, ctab, stab, trigBh, trigBl, trigTh, trigTl, Whi, Wlo);
  k_lift<<<16384, 256, 0, stream>>>((const float4*)q, proj_w, proj_b, (float4*)x);

  for (int d = 0; d < DEPTH; ++d){
    k_dftw<<<512, 256, 0, stream>>>(x, trigTh, trigTl, (float*)X1, (float4*)Xf);
    k_dfth<<<dim3(64,16), 256, 0, stream>>>(X1, ctab, stab, Xf, (float4*)Y);
    k_contract<<<dim3(64,4,4), 64, 0, stream>>>((const float2*)Xf,
                                                spec_wr + (size_t)d*1048576,
                                                spec_wi + (size_t)d*1048576, Y);
    k_idfth<<<2048, 256, 0, stream>>>((const float2*)Y, ctab, stab, Thi, Tlo);
    k_combine<<<dim3(8,512), 256, 0, stream>>>(x, Whi + d*4096, Wlo + d*4096,
                                               Thi, Tlo, trigBh, trigBl,
                                               w_b + d*64, x);
  }
  k_final<<<256, 256, 0, stream>>>(x, final_w, final_b, (float4*)out);
}

// Round 12
// 347.964 us; speedup vs baseline: 1.2847x; 1.0782x over previous
//
#include <hip/hip_runtime.h>
#include <cmath>

#define CC 64
#define HH 512
#define WWID 512
#define HWSZ (HH*WWID)
#define DEPTH 4

typedef __attribute__((ext_vector_type(8))) short short8;
typedef __attribute__((ext_vector_type(4))) float floatx4;

__device__ inline unsigned short f2bf(float f){
  unsigned int u = __float_as_uint(f);
  u += 0x7FFF + ((u >> 16) & 1);          // round-to-nearest-even
  return (unsigned short)(u >> 16);
}
__device__ inline float bf2f(unsigned short h){
  return __uint_as_float(((unsigned int)h) << 16);
}

// ---------------- init ----------------
__global__ void k_init(const float* __restrict__ ww,
                       float* __restrict__ ctab, float* __restrict__ stab,
                       unsigned short* __restrict__ trigBh, unsigned short* __restrict__ trigBl,
                       unsigned short* __restrict__ trigTh, unsigned short* __restrict__ trigTl,
                       unsigned short* __restrict__ Whi, unsigned short* __restrict__ Wlo){
  int idx = blockIdx.x*256 + threadIdx.x;
  if (idx < 8192){
    int pos = idx >> 4, k = idx & 15;
    int r = (pos * k) & 511;
    double ang = (2.0 * 3.14159265358979323846 / 512.0) * (double)r;
    float c = (float)cos(ang), s = (float)sin(ang);
    ctab[idx] = c;  stab[idx] = s;
    unsigned short ch = f2bf(c), sh = f2bf(s);
    unsigned short cl = f2bf(c - bf2f(ch)), sl = f2bf(s - bf2f(sh));
    trigBh[pos*32 + 2*k]     = ch;  trigBl[pos*32 + 2*k]     = cl;
    trigBh[pos*32 + 2*k + 1] = sh;  trigBl[pos*32 + 2*k + 1] = sl;
    trigTh[(2*k)*512 + pos]   = ch;  trigTl[(2*k)*512 + pos]   = cl;
    trigTh[(2*k+1)*512 + pos] = sh;  trigTl[(2*k+1)*512 + pos] = sl;
  } else {
    int t = idx - 8192;                   // < 4*64*64, flat [d][o][i]
    float v = ww[t];
    unsigned short h = f2bf(v);
    Whi[t] = h;  Wlo[t] = f2bf(v - bf2f(h));
  }
}

// ---------------- lift: fp32 x; zero Xf tail (layer-0 dftw accumulator) ----------------
__global__ void k_lift(const float4* __restrict__ q, const float* __restrict__ pw,
                       const float* __restrict__ pb, float4* __restrict__ x,
                       float4* __restrict__ Xfz){
  if (blockIdx.x < 32) Xfz[blockIdx.x*256 + threadIdx.x] = make_float4(0.f,0.f,0.f,0.f);
  int idx = blockIdx.x*256 + threadIdx.x;     // < 64*HW/4
  int c = idx >> 16, p = idx & (HWSZ/4 - 1);
  float4 v = q[p];
  float a = pw[c], b = pb[c];
  v.x = fmaf(a, v.x, b); v.y = fmaf(a, v.y, b);
  v.z = fmaf(a, v.z, b); v.w = fmaf(a, v.w, b);
  x[idx] = v;
}

// ---------------- A+B1 fused: DFT along w (MFMA) -> LDS -> h-partial DFT -> atomicAdd Xf ----------------
// Block b: channel i = b>>3, h range [64*(b&7), +64). Zero-Y tail for this layer's contract.
#define APITCH 136
#define XPITCH 33
__global__ __launch_bounds__(256) void k_dftw(const float* __restrict__ x,
    const unsigned short* __restrict__ trigTh, const unsigned short* __restrict__ trigTl,
    const float* __restrict__ ctab, const float* __restrict__ stab,
    float* __restrict__ Xfa, float4* __restrict__ Yz){
  if (blockIdx.x < 32) Yz[blockIdx.x*256 + threadIdx.x] = make_float4(0.f,0.f,0.f,0.f);

  __shared__ unsigned short Ahs[64*APITCH], Als[64*APITCH];
  __shared__ unsigned short Bhs[32*APITCH], Bls[32*APITCH];
  __shared__ float X1s[64*XPITCH];            // [hh][j]: j=2n -> Re, 2n+1 -> Im
  int row0 = blockIdx.x * 64;                 // rows = i*512 + h
  int i  = row0 >> 9;
  int h0 = row0 & 511;
  int t = threadIdx.x;
  int g = t >> 6, lm = t & 15, lq = (t >> 4) & 3;

  floatx4 acc[2] = {{0.f,0.f,0.f,0.f},{0.f,0.f,0.f,0.f}};

  for (int kc = 0; kc < 4; ++kc){             // K chunks of 128
    {                                         // stage A: 64 rows x 128 k, fp32 -> split bf16
      int r = t >> 2, q = t & 3;
      const float4* src4 = (const float4*)(x + (size_t)(row0 + r)*512 + kc*128 + q*32);
      unsigned int* dh = (unsigned int*)&Ahs[r*APITCH + q*32];
      unsigned int* dl = (unsigned int*)&Als[r*APITCH + q*32];
      #pragma unroll
      for (int u = 0; u < 8; ++u){
        float4 v = src4[u];
        unsigned short h0_ = f2bf(v.x), h1 = f2bf(v.y), h2 = f2bf(v.z), h3 = f2bf(v.w);
        dh[u*2]   = (unsigned)h0_ | ((unsigned)h1 << 16);
        dh[u*2+1] = (unsigned)h2 | ((unsigned)h3 << 16);
        unsigned short g0 = f2bf(v.x - bf2f(h0_)), g1 = f2bf(v.y - bf2f(h1));
        unsigned short g2 = f2bf(v.z - bf2f(h2)), g3 = f2bf(v.w - bf2f(h3));
        dl[u*2]   = (unsigned)g0 | ((unsigned)g1 << 16);
        dl[u*2+1] = (unsigned)g2 | ((unsigned)g3 << 16);
      }
    }
    {                                         // stage B: 32 rows x 128 k (bf16 copy)
      int j = t >> 3, q = t & 7;
      const unsigned int* sh = (const unsigned int*)trigTh + j*256 + kc*64 + q*8;
      const unsigned int* sl = (const unsigned int*)trigTl + j*256 + kc*64 + q*8;
      unsigned int* dh = (unsigned int*)&Bhs[j*APITCH + q*16];
      unsigned int* dl = (unsigned int*)&Bls[j*APITCH + q*16];
      #pragma unroll
      for (int u = 0; u < 8; ++u){ dh[u] = sh[u]; dl[u] = sl[u]; }
    }
    __syncthreads();
    #pragma unroll
    for (int ks = 0; ks < 4; ++ks){
      short8 ah = *(const short8*)&Ahs[(g*16 + lm)*APITCH + ks*32 + lq*8];
      short8 al = *(const short8*)&Als[(g*16 + lm)*APITCH + ks*32 + lq*8];
      #pragma unroll
      for (int nt = 0; nt < 2; ++nt){
        short8 bh = *(const short8*)&Bhs[(nt*16 + lm)*APITCH + ks*32 + lq*8];
        short8 bl = *(const short8*)&Bls[(nt*16 + lm)*APITCH + ks*32 + lq*8];
        acc[nt] = __builtin_amdgcn_mfma_f32_16x16x32_bf16(ah, bh, acc[nt], 0, 0, 0);
        acc[nt] = __builtin_amdgcn_mfma_f32_16x16x32_bf16(ah, bl, acc[nt], 0, 0, 0);
        acc[nt] = __builtin_amdgcn_mfma_f32_16x16x32_bf16(al, bh, acc[nt], 0, 0, 0);
      }
    }
    __syncthreads();
  }
  // D -> LDS (sign-folded): row hh = g*16+lq*4+rg, col j = nt*16+lm; odd j negated
  #pragma unroll
  for (int nt = 0; nt < 2; ++nt){
    int j = nt*16 + lm;
    float sgn = (j & 1) ? -1.f : 1.f;
    #pragma unroll
    for (int rg = 0; rg < 4; ++rg){
      int m = g*16 + lq*4 + rg;
      X1s[m*XPITCH + j] = sgn * acc[nt][rg];
    }
  }
  __syncthreads();

  // h-partial DFT (ex-k_dfth): thread (mo,n) sums its 64 h's, atomicAdd into Xf[i][mn]
  int mo = t >> 4, n = t & 15;
  float ar = 0.f, ai = 0.f;
  #pragma unroll 8
  for (int hh = 0; hh < 64; ++hh){
    int h = h0 + hh;
    float Re = X1s[hh*XPITCH + 2*n];
    float Im = X1s[hh*XPITCH + 2*n + 1];
    float c = ctab[h*16 + mo], s = stab[h*16 + mo];
    ar += Re*c + Im*s;
    ai += Im*c - Re*s;
  }
  atomicAdd(&Xfa[(i*256 + t)*2],     ar);
  atomicAdd(&Xfa[(i*256 + t)*2 + 1], ai);
}

// ---------------- B2: mode contraction, i-chunked, mn-split; atomicAdd into Y ----------------
__global__ void k_contract(const float2* __restrict__ Xf,
                           const float* __restrict__ wr, const float* __restrict__ wi,
                           float* __restrict__ Ya){
  int o = blockIdx.x, ic = blockIdx.y;
  int mn = blockIdx.z*64 + threadIdx.x;
  float ar = 0.f, ai = 0.f;
  int i0 = ic * 16;
  #pragma unroll
  for (int ii = 0; ii < 16; ++ii){
    int i = i0 + ii;
    float2 xf = Xf[i*256 + mn];
    float wrv = wr[(i*64 + o)*256 + mn];
    float wiv = wi[(i*64 + o)*256 + mn];
    ar += xf.x*wrv - xf.y*wiv;
    ai += xf.x*wiv + xf.y*wrv;
  }
  const float sc = 1.f/262144.f;
  atomicAdd(&Ya[(o*256 + mn)*2],     ar*sc);
  atomicAdd(&Ya[(o*256 + mn)*2 + 1], ai*sc);
}

// ---------------- B3: iDFT along h -> T split bf16; zero-Xf tail (next layer's accumulator) ----------------
__global__ void k_idfth(const float2* __restrict__ Y, const float* __restrict__ ct,
                        const float* __restrict__ st,
                        unsigned int* __restrict__ Thi, unsigned int* __restrict__ Tlo,
                        float4* __restrict__ Xfz){
  if (blockIdx.x < 32) Xfz[blockIdx.x*256 + threadIdx.x] = make_float4(0.f,0.f,0.f,0.f);
  int idx = blockIdx.x*256 + threadIdx.x;     // (h*64+o)*16+n
  int n = idx & 15, o = (idx >> 4) & 63, h = idx >> 10;
  float ar = 0.f, ai = 0.f;
  #pragma unroll
  for (int m = 0; m < 16; ++m){
    float2 y = Y[(o<<8) + (m<<4) + n];
    float c = ct[h*16 + m], s = st[h*16 + m];
    ar += y.x*c - y.y*s;
    ai += y.x*s + y.y*c;
  }
  float tr = ar, ts = -ai;
  unsigned short rh = f2bf(tr), sh = f2bf(ts);
  Thi[idx] = (unsigned int)rh | ((unsigned int)sh << 16);   // [2n]=Tr low, [2n+1]=-Ti high
  unsigned short rl = f2bf(tr - bf2f(rh)), slr = f2bf(ts - bf2f(sh));
  Tlo[idx] = (unsigned int)rl | ((unsigned int)slr << 16);
}

// ---------------- C: combine GEMM (K=96), split-bf16 3-pass, fp32 x (R8 verbatim) ----------------
#define PITCH 104
__global__ __launch_bounds__(256) void k_combine(
    const float* __restrict__ x,
    const unsigned short* __restrict__ Whid, const unsigned short* __restrict__ Wlod,
    const unsigned int* __restrict__ Thi,  const unsigned int* __restrict__ Tlo,
    const unsigned short* __restrict__ trigBh, const unsigned short* __restrict__ trigBl,
    const float* __restrict__ wb, float* __restrict__ xo)
{
  __shared__ unsigned short Ah[64*PITCH], Al[64*PITCH];   // rows o, k 0..95
  __shared__ unsigned short Bh[64*PITCH], Bl[64*PITCH];   // rows w(pixel), k 0..95
  int h  = blockIdx.y;
  int w0 = blockIdx.x * 64;
  int t  = threadIdx.x;

  {   // B x-part: coalesced fp32 reads, f2bf split, packed b32 LDS writes
    int wl = t & 63, ig = t >> 6;
    const float* xb = x + (size_t)h*512 + w0 + wl;
    #pragma unroll
    for (int ii = 0; ii < 16; ii += 2){
      int i0 = ig*16 + ii;
      float v0 = xb[(size_t)i0*HWSZ];
      float v1 = xb[(size_t)(i0+1)*HWSZ];
      unsigned short h0 = f2bf(v0), h1 = f2bf(v1);
      unsigned short g0 = f2bf(v0 - bf2f(h0)), g1 = f2bf(v1 - bf2f(h1));
      *(unsigned int*)&Bh[wl*PITCH + i0] = (unsigned int)h0 | ((unsigned int)h1 << 16);
      *(unsigned int*)&Bl[wl*PITCH + i0] = (unsigned int)g0 | ((unsigned int)g1 << 16);
    }
  }
  {   // B trig-part: rows w, k=64..95
    int row = t >> 2, qq = t & 3;
    const unsigned int* sh = (const unsigned int*)trigBh + (size_t)(w0+row)*16 + qq*4;
    const unsigned int* sl = (const unsigned int*)trigBl + (size_t)(w0+row)*16 + qq*4;
    unsigned int* dh = (unsigned int*)&Bh[row*PITCH + 64] + qq*4;
    unsigned int* dl = (unsigned int*)&Bl[row*PITCH + 64] + qq*4;
    #pragma unroll
    for (int u = 0; u < 4; ++u){ dh[u] = sh[u]; dl[u] = sl[u]; }
  }
  {   // A W-part: rows o, k=0..63
    int o = t >> 2, q8 = t & 3;
    const unsigned int* sh = (const unsigned int*)Whid + o*32 + q8*8;
    const unsigned int* sl = (const unsigned int*)Wlod + o*32 + q8*8;
    unsigned int* dh = (unsigned int*)&Ah[o*PITCH] + q8*8;
    unsigned int* dl = (unsigned int*)&Al[o*PITCH] + q8*8;
    #pragma unroll
    for (int u = 0; u < 8; ++u){ dh[u] = sh[u]; dl[u] = sl[u]; }
  }
  {   // A T-part: rows o, k=64..95
    int o = t >> 2, q4 = t & 3;
    const unsigned int* sh = Thi + (size_t)h*1024 + o*16 + q4*4;
    const unsigned int* sl = Tlo + (size_t)h*1024 + o*16 + q4*4;
    unsigned int* dh = (unsigned int*)&Ah[o*PITCH + 64] + q4*4;
    unsigned int* dl = (unsigned int*)&Al[o*PITCH + 64] + q4*4;
    #pragma unroll
    for (int u = 0; u < 4; ++u){ dh[u] = sh[u]; dl[u] = sl[u]; }
  }
  __syncthreads();

  int g  = t >> 6;          // wave -> m-tile (o-rows g*16..+15)
  int lm = t & 15;
  int lq = (t >> 4) & 3;

  floatx4 acc[4] = {{0.f,0.f,0.f,0.f},{0.f,0.f,0.f,0.f},{0.f,0.f,0.f,0.f},{0.f,0.f,0.f,0.f}};

  #pragma unroll
  for (int ks = 0; ks < 3; ++ks){
    short8 af = *(const short8*)&Ah[(g*16 + lm)*PITCH + ks*32 + lq*8];
    short8 al = *(const short8*)&Al[(g*16 + lm)*PITCH + ks*32 + lq*8];
    #pragma unroll
    for (int nt = 0; nt < 4; ++nt){
      short8 bf = *(const short8*)&Bh[(nt*16 + lm)*PITCH + ks*32 + lq*8];
      short8 bl = *(const short8*)&Bl[(nt*16 + lm)*PITCH + ks*32 + lq*8];
      acc[nt] = __builtin_amdgcn_mfma_f32_16x16x32_bf16(af, bf, acc[nt], 0, 0, 0);
      acc[nt] = __builtin_amdgcn_mfma_f32_16x16x32_bf16(af, bl, acc[nt], 0, 0, 0);
      acc[nt] = __builtin_amdgcn_mfma_f32_16x16x32_bf16(al, bf, acc[nt], 0, 0, 0);
    }
  }

  // epilogue: bias + tanh-gelu + fp32 in-place store
  #pragma unroll
  for (int nt = 0; nt < 4; ++nt){
    int w = w0 + nt*16 + lm;
    #pragma unroll
    for (int rg = 0; rg < 4; ++rg){
      int o = g*16 + lq*4 + rg;
      float u = acc[nt][rg] + wb[o];
      float z = 0.7978845608028654f * fmaf(0.044715f, u*u*u, u);
      float e = __expf(2.f*z);
      float gl = u - __fdividef(u, e + 1.f);
      xo[(size_t)o*HWSZ + (size_t)h*512 + w] = gl;
    }
  }
}

// ---------------- final projection (float4) ----------------
__global__ void k_final(const float* __restrict__ x, const float* __restrict__ fw,
                        const float* __restrict__ fb, float4* __restrict__ out){
  int p4 = blockIdx.x*256 + threadIdx.x;      // < HW/4 = 65536
  float b = fb[0];
  float4 acc = make_float4(b, b, b, b);
  #pragma unroll
  for (int i = 0; i < CC; ++i){
    float4 v = *(const float4*)(x + (size_t)i*HWSZ + (size_t)p4*4);
    float wv = fw[i];
    acc.x = fmaf(wv, v.x, acc.x); acc.y = fmaf(wv, v.y, acc.y);
    acc.z = fmaf(wv, v.z, acc.z); acc.w = fmaf(wv, v.w, acc.w);
  }
  out[p4] = acc;
}

extern "C" void kernel_launch(void* const* d_in, const int* in_sizes, int n_in,
                              void* d_out, int out_size, void* d_ws, size_t ws_size,
                              hipStream_t stream) {
  const float* q       = (const float*)d_in[0];
  const float* proj_w  = (const float*)d_in[1];
  const float* proj_b  = (const float*)d_in[2];
  const float* spec_wr = (const float*)d_in[3];
  const float* spec_wi = (const float*)d_in[4];
  const float* w_w     = (const float*)d_in[5];
  const float* w_b     = (const float*)d_in[6];
  const float* final_w = (const float*)d_in[7];
  const float* final_b = (const float*)d_in[8];
  float* out = (float*)d_out;

  // Workspace (bytes, end-exclusive) — X1 eliminated (dftw+dfth fused in LDS):
  //   ctab   [       0,   32768)
  //   stab   [   32768,   65536)
  //   trigBh [   65536,   98304)   trigBl [   98304,  131072)
  //   Thi    [  131072,  2228224)  Tlo [ 2228224,  4325376)
  //   Xf     [ 4325376,  4456448)  128 KiB (dftw atomics; zeroed by lift/idfth tails)
  //   Y      [ 4456448,  4587520)  128 KiB (contract atomics; zeroed by dftw tail)
  //   x      [ 4587520, 71696384)  64 MiB fp32
  //   Whi    [71696384, 71729152)  Wlo [71729152, 71761920)
  //   trigTh [71761920, 71794688)  trigTl [71794688, 71827456)   total ~68.5 MiB
  char* ws = (char*)d_ws;
  float*  ctab = (float*) (ws + 0);
  float*  stab = (float*) (ws + 32768);
  unsigned short* trigBh = (unsigned short*)(ws + 65536);
  unsigned short* trigBl = (unsigned short*)(ws + 98304);
  unsigned int* Thi = (unsigned int*)(ws + 131072);
  unsigned int* Tlo = (unsigned int*)(ws + 2228224);
  float*  Xf   = (float*) (ws + 4325376);
  float*  Y    = (float*) (ws + 4456448);
  float*  x    = (float*) (ws + 4587520);
  unsigned short* Whi = (unsigned short*)(ws + 71696384);
  unsigned short* Wlo = (unsigned short*)(ws + 71729152);
  unsigned short* trigTh = (unsigned short*)(ws + 71761920);
  unsigned short* trigTl = (unsigned short*)(ws + 71794688);

  k_init<<<96, 256, 0, stream>>>(w_w, ctab, stab, trigBh, trigBl, trigTh, trigTl, Whi, Wlo);
  k_lift<<<16384, 256, 0, stream>>>((const float4*)q, proj_w, proj_b, (float4*)x,
                                    (float4*)Xf);

  for (int d = 0; d < DEPTH; ++d){
    k_dftw<<<512, 256, 0, stream>>>(x, trigTh, trigTl, ctab, stab, Xf, (float4*)Y);
    k_contract<<<dim3(64,4,4), 64, 0, stream>>>((const float2*)Xf,
                                                spec_wr + (size_t)d*1048576,
                                                spec_wi + (size_t)d*1048576, Y);
    k_idfth<<<2048, 256, 0, stream>>>((const float2*)Y, ctab, stab, Thi, Tlo,
                                      (float4*)Xf);
    k_combine<<<dim3(8,512), 256, 0, stream>>>(x, Whi + d*4096, Wlo + d*4096,
                                               Thi, Tlo, trigBh, trigBl,
                                               w_b + d*64, x);
  }
  k_final<<<256, 256, 0, stream>>>(x, final_w, final_b, (float4*)out);
}

// Round 13
// 317.472 us; speedup vs baseline: 1.4081x; 1.0960x over previous
//
#include <hip/hip_runtime.h>
#include <cmath>

#define CC 64
#define HH 512
#define WWID 512
#define HWSZ (HH*WWID)
#define DEPTH 4

typedef __attribute__((ext_vector_type(8))) short short8;
typedef __attribute__((ext_vector_type(4))) float floatx4;

__device__ inline unsigned short f2bf(float f){
  unsigned int u = __float_as_uint(f);
  u += 0x7FFF + ((u >> 16) & 1);          // round-to-nearest-even
  return (unsigned short)(u >> 16);
}
__device__ inline float bf2f(unsigned short h){
  return __uint_as_float(((unsigned int)h) << 16);
}

// ---------------- init (+ zero Xf for layer-0 dftw atomics) ----------------
__global__ void k_init(const float* __restrict__ ww,
                       float* __restrict__ ctab, float* __restrict__ stab,
                       unsigned short* __restrict__ trigBh, unsigned short* __restrict__ trigBl,
                       unsigned short* __restrict__ trigTh, unsigned short* __restrict__ trigTl,
                       unsigned short* __restrict__ Whi, unsigned short* __restrict__ Wlo,
                       float4* __restrict__ Xfz){
  if (blockIdx.x < 32) Xfz[blockIdx.x*256 + threadIdx.x] = make_float4(0.f,0.f,0.f,0.f);
  int idx = blockIdx.x*256 + threadIdx.x;
  if (idx < 8192){
    int pos = idx >> 4, k = idx & 15;
    int r = (pos * k) & 511;
    double ang = (2.0 * 3.14159265358979323846 / 512.0) * (double)r;
    float c = (float)cos(ang), s = (float)sin(ang);
    ctab[idx] = c;  stab[idx] = s;
    unsigned short ch = f2bf(c), sh = f2bf(s);
    unsigned short cl = f2bf(c - bf2f(ch)), sl = f2bf(s - bf2f(sh));
    trigBh[pos*32 + 2*k]     = ch;  trigBl[pos*32 + 2*k]     = cl;
    trigBh[pos*32 + 2*k + 1] = sh;  trigBl[pos*32 + 2*k + 1] = sl;
    trigTh[(2*k)*512 + pos]   = ch;  trigTl[(2*k)*512 + pos]   = cl;
    trigTh[(2*k+1)*512 + pos] = sh;  trigTl[(2*k+1)*512 + pos] = sl;
  } else {
    int t = idx - 8192;                   // < 4*64*64, flat [d][o][i]
    float v = ww[t];
    unsigned short h = f2bf(v);
    Whi[t] = h;  Wlo[t] = f2bf(v - bf2f(h));
  }
}

// ---------------- A+B1 fused: DFT along w (MFMA) -> LDS -> h-partial DFT -> atomicAdd Xf ----------------
// Block b: channel i = b>>3, h range [64*(b&7), +64). LIFT=1: read q + on-the-fly lift (layer 0).
#define APITCH 136
#define XPITCH 33
template<int LIFT>
__global__ __launch_bounds__(256) void k_dftw(const float* __restrict__ x,
    const float* __restrict__ qsrc, const float* __restrict__ pw, const float* __restrict__ pb,
    const unsigned short* __restrict__ trigTh, const unsigned short* __restrict__ trigTl,
    const float* __restrict__ ctab, const float* __restrict__ stab,
    float* __restrict__ Xfa, float4* __restrict__ Yz){
  if (blockIdx.x < 32) Yz[blockIdx.x*256 + threadIdx.x] = make_float4(0.f,0.f,0.f,0.f);

  __shared__ unsigned short Ahs[64*APITCH], Als[64*APITCH];
  __shared__ unsigned short Bhs[32*APITCH], Bls[32*APITCH];
  __shared__ float X1s[64*XPITCH];            // [hh][j]: j=2n -> Re, 2n+1 -> Im
  int row0 = blockIdx.x * 64;                 // rows = i*512 + h
  int i  = row0 >> 9;
  int h0 = row0 & 511;
  int t = threadIdx.x;
  int g = t >> 6, lm = t & 15, lq = (t >> 4) & 3;
  float pa = 0.f, pbv = 0.f;
  if (LIFT){ pa = pw[i]; pbv = pb[i]; }       // block-uniform scalars

  floatx4 acc[2] = {{0.f,0.f,0.f,0.f},{0.f,0.f,0.f,0.f}};

  for (int kc = 0; kc < 4; ++kc){             // K chunks of 128
    {                                         // stage A: 64 rows x 128 k, fp32 -> split bf16
      int r = t >> 2, qq = t & 3;
      const float4* src4 = LIFT
        ? (const float4*)(qsrc + (size_t)(h0 + r)*512 + kc*128 + qq*32)
        : (const float4*)(x    + (size_t)(row0 + r)*512 + kc*128 + qq*32);
      unsigned int* dh = (unsigned int*)&Ahs[r*APITCH + qq*32];
      unsigned int* dl = (unsigned int*)&Als[r*APITCH + qq*32];
      #pragma unroll
      for (int u = 0; u < 8; ++u){
        float4 v = src4[u];
        if (LIFT){
          v.x = fmaf(pa, v.x, pbv); v.y = fmaf(pa, v.y, pbv);
          v.z = fmaf(pa, v.z, pbv); v.w = fmaf(pa, v.w, pbv);
        }
        unsigned short h0_ = f2bf(v.x), h1 = f2bf(v.y), h2 = f2bf(v.z), h3 = f2bf(v.w);
        dh[u*2]   = (unsigned)h0_ | ((unsigned)h1 << 16);
        dh[u*2+1] = (unsigned)h2 | ((unsigned)h3 << 16);
        unsigned short g0 = f2bf(v.x - bf2f(h0_)), g1 = f2bf(v.y - bf2f(h1));
        unsigned short g2 = f2bf(v.z - bf2f(h2)), g3 = f2bf(v.w - bf2f(h3));
        dl[u*2]   = (unsigned)g0 | ((unsigned)g1 << 16);
        dl[u*2+1] = (unsigned)g2 | ((unsigned)g3 << 16);
      }
    }
    {                                         // stage B: 32 rows x 128 k (bf16 copy)
      int j = t >> 3, qq = t & 7;
      const unsigned int* sh = (const unsigned int*)trigTh + j*256 + kc*64 + qq*8;
      const unsigned int* sl = (const unsigned int*)trigTl + j*256 + kc*64 + qq*8;
      unsigned int* dh = (unsigned int*)&Bhs[j*APITCH + qq*16];
      unsigned int* dl = (unsigned int*)&Bls[j*APITCH + qq*16];
      #pragma unroll
      for (int u = 0; u < 8; ++u){ dh[u] = sh[u]; dl[u] = sl[u]; }
    }
    __syncthreads();
    #pragma unroll
    for (int ks = 0; ks < 4; ++ks){
      short8 ah = *(const short8*)&Ahs[(g*16 + lm)*APITCH + ks*32 + lq*8];
      short8 al = *(const short8*)&Als[(g*16 + lm)*APITCH + ks*32 + lq*8];
      #pragma unroll
      for (int nt = 0; nt < 2; ++nt){
        short8 bh = *(const short8*)&Bhs[(nt*16 + lm)*APITCH + ks*32 + lq*8];
        short8 bl = *(const short8*)&Bls[(nt*16 + lm)*APITCH + ks*32 + lq*8];
        acc[nt] = __builtin_amdgcn_mfma_f32_16x16x32_bf16(ah, bh, acc[nt], 0, 0, 0);
        acc[nt] = __builtin_amdgcn_mfma_f32_16x16x32_bf16(ah, bl, acc[nt], 0, 0, 0);
        acc[nt] = __builtin_amdgcn_mfma_f32_16x16x32_bf16(al, bh, acc[nt], 0, 0, 0);
      }
    }
    __syncthreads();
  }
  // D -> LDS (sign-folded): row hh = g*16+lq*4+rg, col j = nt*16+lm; odd j negated
  #pragma unroll
  for (int nt = 0; nt < 2; ++nt){
    int j = nt*16 + lm;
    float sgn = (j & 1) ? -1.f : 1.f;
    #pragma unroll
    for (int rg = 0; rg < 4; ++rg){
      int m = g*16 + lq*4 + rg;
      X1s[m*XPITCH + j] = sgn * acc[nt][rg];
    }
  }
  __syncthreads();

  // h-partial DFT: thread (mo,n) sums its 64 h's, atomicAdd into Xf[i][mn]
  int mo = t >> 4, n = t & 15;
  float ar = 0.f, ai = 0.f;
  #pragma unroll 8
  for (int hh = 0; hh < 64; ++hh){
    int h = h0 + hh;
    float Re = X1s[hh*XPITCH + 2*n];
    float Im = X1s[hh*XPITCH + 2*n + 1];
    float c = ctab[h*16 + mo], s = stab[h*16 + mo];
    ar += Re*c + Im*s;
    ai += Im*c - Re*s;
  }
  atomicAdd(&Xfa[(i*256 + t)*2],     ar);
  atomicAdd(&Xfa[(i*256 + t)*2 + 1], ai);
}

// ---------------- B2: mode contraction, i-chunked, mn-split; atomicAdd into Y ----------------
__global__ void k_contract(const float2* __restrict__ Xf,
                           const float* __restrict__ wr, const float* __restrict__ wi,
                           float* __restrict__ Ya){
  int o = blockIdx.x, ic = blockIdx.y;
  int mn = blockIdx.z*64 + threadIdx.x;
  float ar = 0.f, ai = 0.f;
  int i0 = ic * 16;
  #pragma unroll
  for (int ii = 0; ii < 16; ++ii){
    int i = i0 + ii;
    float2 xf = Xf[i*256 + mn];
    float wrv = wr[(i*64 + o)*256 + mn];
    float wiv = wi[(i*64 + o)*256 + mn];
    ar += xf.x*wrv - xf.y*wiv;
    ai += xf.x*wiv + xf.y*wrv;
  }
  const float sc = 1.f/262144.f;
  atomicAdd(&Ya[(o*256 + mn)*2],     ar*sc);
  atomicAdd(&Ya[(o*256 + mn)*2 + 1], ai*sc);
}

// ---------------- B3: iDFT along h -> T split bf16; zero-Xf tail (next layer's accumulator) ----------------
__global__ void k_idfth(const float2* __restrict__ Y, const float* __restrict__ ct,
                        const float* __restrict__ st,
                        unsigned int* __restrict__ Thi, unsigned int* __restrict__ Tlo,
                        float4* __restrict__ Xfz){
  if (blockIdx.x < 32) Xfz[blockIdx.x*256 + threadIdx.x] = make_float4(0.f,0.f,0.f,0.f);
  int idx = blockIdx.x*256 + threadIdx.x;     // (h*64+o)*16+n
  int n = idx & 15, o = (idx >> 4) & 63, h = idx >> 10;
  float ar = 0.f, ai = 0.f;
  #pragma unroll
  for (int m = 0; m < 16; ++m){
    float2 y = Y[(o<<8) + (m<<4) + n];
    float c = ct[h*16 + m], s = st[h*16 + m];
    ar += y.x*c - y.y*s;
    ai += y.x*s + y.y*c;
  }
  float tr = ar, ts = -ai;
  unsigned short rh = f2bf(tr), sh = f2bf(ts);
  Thi[idx] = (unsigned int)rh | ((unsigned int)sh << 16);   // [2n]=Tr low, [2n+1]=-Ti high
  unsigned short rl = f2bf(tr - bf2f(rh)), slr = f2bf(ts - bf2f(sh));
  Tlo[idx] = (unsigned int)rl | ((unsigned int)slr << 16);
}

// ---------------- C: combine GEMM (K=96), split-bf16 3-pass ----------------
// LIFT=1: x-stage computes lift(q) on the fly (layer 0). FINAL=1: skip x store,
// reduce sum_o fw[o]*gelu -> out (layer 3; fuses k_final).
#define PITCH 104
template<int LIFT, int FINAL>
__global__ __launch_bounds__(256) void k_combine(
    const float* __restrict__ x, const float* __restrict__ qsrc,
    const float* __restrict__ pw, const float* __restrict__ pb,
    const unsigned short* __restrict__ Whid, const unsigned short* __restrict__ Wlod,
    const unsigned int* __restrict__ Thi,  const unsigned int* __restrict__ Tlo,
    const unsigned short* __restrict__ trigBh, const unsigned short* __restrict__ trigBl,
    const float* __restrict__ wb, float* __restrict__ xo,
    const float* __restrict__ fw, const float* __restrict__ fb,
    float* __restrict__ outp)
{
  __shared__ unsigned short Ah[64*PITCH], Al[64*PITCH];   // rows o, k 0..95
  __shared__ unsigned short Bh[64*PITCH], Bl[64*PITCH];   // rows w(pixel), k 0..95
  int h  = blockIdx.y;
  int w0 = blockIdx.x * 64;
  int t  = threadIdx.x;

  {   // B x-part
    int wl = t & 63, ig = t >> 6;
    if (LIFT){
      float qv = qsrc[(size_t)h*512 + w0 + wl];
      #pragma unroll
      for (int ii = 0; ii < 16; ii += 2){
        int i0 = ig*16 + ii;
        float v0 = fmaf(pw[i0],   qv, pb[i0]);
        float v1 = fmaf(pw[i0+1], qv, pb[i0+1]);
        unsigned short h0 = f2bf(v0), h1 = f2bf(v1);
        unsigned short g0 = f2bf(v0 - bf2f(h0)), g1 = f2bf(v1 - bf2f(h1));
        *(unsigned int*)&Bh[wl*PITCH + i0] = (unsigned int)h0 | ((unsigned int)h1 << 16);
        *(unsigned int*)&Bl[wl*PITCH + i0] = (unsigned int)g0 | ((unsigned int)g1 << 16);
      }
    } else {
      const float* xb = x + (size_t)h*512 + w0 + wl;
      #pragma unroll
      for (int ii = 0; ii < 16; ii += 2){
        int i0 = ig*16 + ii;
        float v0 = xb[(size_t)i0*HWSZ];
        float v1 = xb[(size_t)(i0+1)*HWSZ];
        unsigned short h0 = f2bf(v0), h1 = f2bf(v1);
        unsigned short g0 = f2bf(v0 - bf2f(h0)), g1 = f2bf(v1 - bf2f(h1));
        *(unsigned int*)&Bh[wl*PITCH + i0] = (unsigned int)h0 | ((unsigned int)h1 << 16);
        *(unsigned int*)&Bl[wl*PITCH + i0] = (unsigned int)g0 | ((unsigned int)g1 << 16);
      }
    }
  }
  {   // B trig-part: rows w, k=64..95
    int row = t >> 2, qq = t & 3;
    const unsigned int* sh = (const unsigned int*)trigBh + (size_t)(w0+row)*16 + qq*4;
    const unsigned int* sl = (const unsigned int*)trigBl + (size_t)(w0+row)*16 + qq*4;
    unsigned int* dh = (unsigned int*)&Bh[row*PITCH + 64] + qq*4;
    unsigned int* dl = (unsigned int*)&Bl[row*PITCH + 64] + qq*4;
    #pragma unroll
    for (int u = 0; u < 4; ++u){ dh[u] = sh[u]; dl[u] = sl[u]; }
  }
  {   // A W-part: rows o, k=0..63
    int o = t >> 2, q8 = t & 3;
    const unsigned int* sh = (const unsigned int*)Whid + o*32 + q8*8;
    const unsigned int* sl = (const unsigned int*)Wlod + o*32 + q8*8;
    unsigned int* dh = (unsigned int*)&Ah[o*PITCH] + q8*8;
    unsigned int* dl = (unsigned int*)&Al[o*PITCH] + q8*8;
    #pragma unroll
    for (int u = 0; u < 8; ++u){ dh[u] = sh[u]; dl[u] = sl[u]; }
  }
  {   // A T-part: rows o, k=64..95
    int o = t >> 2, q4 = t & 3;
    const unsigned int* sh = Thi + (size_t)h*1024 + o*16 + q4*4;
    const unsigned int* sl = Tlo + (size_t)h*1024 + o*16 + q4*4;
    unsigned int* dh = (unsigned int*)&Ah[o*PITCH + 64] + q4*4;
    unsigned int* dl = (unsigned int*)&Al[o*PITCH + 64] + q4*4;
    #pragma unroll
    for (int u = 0; u < 4; ++u){ dh[u] = sh[u]; dl[u] = sl[u]; }
  }
  __syncthreads();

  int g  = t >> 6;          // wave -> m-tile (o-rows g*16..+15)
  int lm = t & 15;
  int lq = (t >> 4) & 3;

  floatx4 acc[4] = {{0.f,0.f,0.f,0.f},{0.f,0.f,0.f,0.f},{0.f,0.f,0.f,0.f},{0.f,0.f,0.f,0.f}};

  #pragma unroll
  for (int ks = 0; ks < 3; ++ks){
    short8 af = *(const short8*)&Ah[(g*16 + lm)*PITCH + ks*32 + lq*8];
    short8 al = *(const short8*)&Al[(g*16 + lm)*PITCH + ks*32 + lq*8];
    #pragma unroll
    for (int nt = 0; nt < 4; ++nt){
      short8 bf = *(const short8*)&Bh[(nt*16 + lm)*PITCH + ks*32 + lq*8];
      short8 bl = *(const short8*)&Bl[(nt*16 + lm)*PITCH + ks*32 + lq*8];
      acc[nt] = __builtin_amdgcn_mfma_f32_16x16x32_bf16(af, bf, acc[nt], 0, 0, 0);
      acc[nt] = __builtin_amdgcn_mfma_f32_16x16x32_bf16(af, bl, acc[nt], 0, 0, 0);
      acc[nt] = __builtin_amdgcn_mfma_f32_16x16x32_bf16(al, bf, acc[nt], 0, 0, 0);
    }
  }

  if (!FINAL){
    // epilogue: bias + tanh-gelu + fp32 in-place store
    #pragma unroll
    for (int nt = 0; nt < 4; ++nt){
      int w = w0 + nt*16 + lm;
      #pragma unroll
      for (int rg = 0; rg < 4; ++rg){
        int o = g*16 + lq*4 + rg;
        float u = acc[nt][rg] + wb[o];
        float z = 0.7978845608028654f * fmaf(0.044715f, u*u*u, u);
        float e = __expf(2.f*z);
        float gl = u - __fdividef(u, e + 1.f);
        xo[(size_t)o*HWSZ + (size_t)h*512 + w] = gl;
      }
    }
  } else {
    // epilogue: bias + gelu + final projection reduced in-block (fuses k_final)
    __shared__ float fred[64*17];             // [w_local][slot g*4+lq], +1 pad
    #pragma unroll
    for (int nt = 0; nt < 4; ++nt){
      float partial = 0.f;
      #pragma unroll
      for (int rg = 0; rg < 4; ++rg){
        int o = g*16 + lq*4 + rg;
        float u = acc[nt][rg] + wb[o];
        float z = 0.7978845608028654f * fmaf(0.044715f, u*u*u, u);
        float e = __expf(2.f*z);
        float gl = u - __fdividef(u, e + 1.f);
        partial = fmaf(fw[o], gl, partial);
      }
      fred[(nt*16 + lm)*17 + (t >> 4)] = partial;
    }
    __syncthreads();
    if (t < 64){
      float s = fb[0];
      #pragma unroll
      for (int k2 = 0; k2 < 16; ++k2) s += fred[t*17 + k2];
      outp[(size_t)h*512 + w0 + t] = s;
    }
  }
}

extern "C" void kernel_launch(void* const* d_in, const int* in_sizes, int n_in,
                              void* d_out, int out_size, void* d_ws, size_t ws_size,
                              hipStream_t stream) {
  const float* q       = (const float*)d_in[0];
  const float* proj_w  = (const float*)d_in[1];
  const float* proj_b  = (const float*)d_in[2];
  const float* spec_wr = (const float*)d_in[3];
  const float* spec_wi = (const float*)d_in[4];
  const float* w_w     = (const float*)d_in[5];
  const float* w_b     = (const float*)d_in[6];
  const float* final_w = (const float*)d_in[7];
  const float* final_b = (const float*)d_in[8];
  float* out = (float*)d_out;

  // Workspace (bytes, end-exclusive) — same as R12:
  //   ctab   [       0,   32768)
  //   stab   [   32768,   65536)
  //   trigBh [   65536,   98304)   trigBl [   98304,  131072)
  //   Thi    [  131072,  2228224)  Tlo [ 2228224,  4325376)
  //   Xf     [ 4325376,  4456448)  128 KiB (dftw atomics; zeroed by init/idfth tails)
  //   Y      [ 4456448,  4587520)  128 KiB (contract atomics; zeroed by dftw tail)
  //   x      [ 4587520, 71696384)  64 MiB fp32 (layers 0-2 activations)
  //   Whi    [71696384, 71729152)  Wlo [71729152, 71761920)
  //   trigTh [71761920, 71794688)  trigTl [71794688, 71827456)   total ~68.5 MiB
  char* ws = (char*)d_ws;
  float*  ctab = (float*) (ws + 0);
  float*  stab = (float*) (ws + 32768);
  unsigned short* trigBh = (unsigned short*)(ws + 65536);
  unsigned short* trigBl = (unsigned short*)(ws + 98304);
  unsigned int* Thi = (unsigned int*)(ws + 131072);
  unsigned int* Tlo = (unsigned int*)(ws + 2228224);
  float*  Xf   = (float*) (ws + 4325376);
  float*  Y    = (float*) (ws + 4456448);
  float*  x    = (float*) (ws + 4587520);
  unsigned short* Whi = (unsigned short*)(ws + 71696384);
  unsigned short* Wlo = (unsigned short*)(ws + 71729152);
  unsigned short* trigTh = (unsigned short*)(ws + 71761920);
  unsigned short* trigTl = (unsigned short*)(ws + 71794688);

  k_init<<<96, 256, 0, stream>>>(w_w, ctab, stab, trigBh, trigBl, trigTh, trigTl,
                                 Whi, Wlo, (float4*)Xf);

  for (int d = 0; d < DEPTH; ++d){
    if (d == 0)
      k_dftw<1><<<512, 256, 0, stream>>>(x, q, proj_w, proj_b, trigTh, trigTl,
                                         ctab, stab, Xf, (float4*)Y);
    else
      k_dftw<0><<<512, 256, 0, stream>>>(x, q, proj_w, proj_b, trigTh, trigTl,
                                         ctab, stab, Xf, (float4*)Y);
    k_contract<<<dim3(64,4,4), 64, 0, stream>>>((const float2*)Xf,
                                                spec_wr + (size_t)d*1048576,
                                                spec_wi + (size_t)d*1048576, Y);
    k_idfth<<<2048, 256, 0, stream>>>((const float2*)Y, ctab, stab, Thi, Tlo,
                                      (float4*)Xf);
    if (d == 0)
      k_combine<1,0><<<dim3(8,512), 256, 0, stream>>>(x, q, proj_w, proj_b,
          Whi + d*4096, Wlo + d*4096, Thi, Tlo, trigBh, trigBl,
          w_b + d*64, x, final_w, final_b, out);
    else if (d < DEPTH-1)
      k_combine<0,0><<<dim3(8,512), 256, 0, stream>>>(x, q, proj_w, proj_b,
          Whi + d*4096, Wlo + d*4096, Thi, Tlo, trigBh, trigBl,
          w_b + d*64, x, final_w, final_b, out);
    else
      k_combine<0,1><<<dim3(8,512), 256, 0, stream>>>(x, q, proj_w, proj_b,
          Whi + d*4096, Wlo + d*4096, Thi, Tlo, trigBh, trigBl,
          w_b + d*64, x, final_w, final_b, out);
  }
}